// Round 1
// baseline (5085.599 us; speedup 1.0000x reference)
//
#include <hip/hip_runtime.h>
#include <stdint.h>

// Problem constants (fixed by setup_inputs)
#define DD   1024
#define GNUM 64

typedef __attribute__((ext_vector_type(8))) short short8;
typedef __attribute__((ext_vector_type(4))) float f32x4;

__device__ __forceinline__ ushort f2bf(float f) {
    unsigned u = __float_as_uint(f);
    u += 0x7FFFu + ((u >> 16) & 1u);   // RNE
    return (ushort)(u >> 16);
}
__device__ __forceinline__ float bf2f(ushort h) {
    return __uint_as_float(((unsigned)h) << 16);
}
// order-preserving float->u32 encoding for atomicMax
__device__ __forceinline__ unsigned enc_f(float f) {
    unsigned u = __float_as_uint(f);
    return (u & 0x80000000u) ? ~u : (u | 0x80000000u);
}
__device__ __forceinline__ float dec_f(unsigned m) {
    unsigned u = (m & 0x80000000u) ? (m & 0x7FFFFFFFu) : ~m;
    return __uint_as_float(u);
}
#define SENT 0x007FFFFFu   // enc(-inf): no finite float maps here

__device__ __forceinline__ void load_lds16(const void* g, void* l) {
    __builtin_amdgcn_global_load_lds(
        (const __attribute__((address_space(1))) unsigned*)(uintptr_t)g,
        (__attribute__((address_space(3))) unsigned*)(uint32_t)(uintptr_t)l,
        16, 0, 0);
}

__device__ __forceinline__ int lbound(const int* a, int n, int v) {
    int lo = 0, hi = n;
    while (lo < hi) { int m = (lo + hi) >> 1; if (a[m] < v) lo = m + 1; else hi = m; }
    return lo;
}

// ---------------------------------------------------------------------------
// Build WbigT [4096][1024] bf16 (transposed weights, BN scale folded in).
// c in [0,1024): blk1 U = (W1[k][c]-W1[k+1024][c])*s1[c]
// c in [1024,2048): blk1 V = W1[k+1024][cl]*s1[cl]
// c in [2048,3072): blk2 U ;  c in [3072,4096): blk2 V
// ---------------------------------------------------------------------------
__global__ __launch_bounds__(256) void wbig_kernel(
    const float* __restrict__ W1, const float* __restrict__ W2,
    const float* __restrict__ g1, const float* __restrict__ g2,
    ushort* __restrict__ Wt)
{
    __shared__ float tile[32][33];
    const float SF = 1.0f / sqrtf(1.0f + 1e-5f);
    int k0 = blockIdx.x * 32, c0 = blockIdx.y * 32;
    int tx = threadIdx.x & 31, ty = threadIdx.x >> 5;  // ty 0..7
    int sec = c0 >> 10;
    int cl = (c0 & 1023) + tx;
    const float* W  = (sec < 2) ? W1 : W2;
    const float* gv = (sec < 2) ? g1 : g2;
    bool isU = (sec & 1) == 0;
    float sc = gv[cl] * SF;
    #pragma unroll
    for (int j = 0; j < 4; ++j) {
        int k = k0 + ty + j * 8;
        float v = isU ? (W[(size_t)k * 1024 + cl] - W[(size_t)(k + 1024) * 1024 + cl]) * sc
                      : W[(size_t)(k + 1024) * 1024 + cl] * sc;
        tile[ty + j * 8][tx] = v;
    }
    __syncthreads();
    #pragma unroll
    for (int j = 0; j < 4; ++j) {
        int cc = ty + j * 8;
        Wt[(size_t)(c0 + cc) * 1024 + k0 + tx] = f2bf(tile[tx][cc]);
    }
}

__global__ __launch_bounds__(256) void bias_kernel(
    const float* __restrict__ b1, const float* __restrict__ g1, const float* __restrict__ be1,
    const float* __restrict__ b2, const float* __restrict__ g2, const float* __restrict__ be2,
    float* __restrict__ biasv)
{
    const float SF = 1.0f / sqrtf(1.0f + 1e-5f);
    int c = blockIdx.x * 256 + threadIdx.x;  // 0..4095
    int sec = c >> 10, cl = c & 1023;
    float v = 0.0f;
    if (sec == 0) v = b1[cl] * (g1[cl] * SF) + be1[cl];
    else if (sec == 2) v = b2[cl] * (g2[cl] * SF) + be2[cl];
    biasv[c] = v;
}

__global__ __launch_bounds__(256) void cvt_kernel(
    const float* __restrict__ x, ushort* __restrict__ xh)
{
    size_t i = ((size_t)blockIdx.x * 256 + threadIdx.x) * 8;
    const float4 a = *(const float4*)(x + i);
    const float4 b = *(const float4*)(x + i + 4);
    ushort4 lo = make_ushort4(f2bf(a.x), f2bf(a.y), f2bf(a.z), f2bf(a.w));
    ushort4 hi = make_ushort4(f2bf(b.x), f2bf(b.y), f2bf(b.z), f2bf(b.w));
    *(ushort4*)(xh + i) = lo;
    *(ushort4*)(xh + i + 4) = hi;
}

// per-graph mean of x  -> Xbar [64][1024]  (deterministic: contiguous ranges)
__global__ __launch_bounds__(256) void segmean_kernel(
    const float* __restrict__ x, const int* __restrict__ batch,
    float* __restrict__ Xbar, int N)
{
    int g = blockIdx.x >> 2;
    int d = ((blockIdx.x & 3) << 8) + threadIdx.x;
    int lo = lbound(batch, N, g);
    int hi = lbound(batch, N, g + 1);
    float s = 0.0f;
    for (int i = lo; i < hi; ++i) s += x[(size_t)i * 1024 + d];
    int cnt = hi - lo; if (cnt < 1) cnt = 1;
    Xbar[g * 1024 + d] = s / (float)cnt;
}

// Wfold[k][o] = sum_c W0[k][c]*s0[c]*Wr[c][o]   (block-0 collapsed into final)
__global__ __launch_bounds__(256) void wfold_kernel(
    const float* __restrict__ W0, const float* __restrict__ g0,
    const float* __restrict__ Wr, float* __restrict__ Wfold)
{
    __shared__ float sWr[2048];
    __shared__ float sS[1024];
    const float SF = 1.0f / sqrtf(1.0f + 1e-5f);
    for (int i = threadIdx.x; i < 2048; i += 256) sWr[i] = Wr[i];
    for (int i = threadIdx.x; i < 1024; i += 256) sS[i] = g0[i] * SF;
    __syncthreads();
    int k = blockIdx.x * 256 + threadIdx.x;  // 0..1023
    const float* row = W0 + (size_t)k * 1024;
    float a0 = 0.0f, a1 = 0.0f;
    for (int c = 0; c < 1024; ++c) {
        float w = row[c] * sS[c];
        a0 += w * sWr[c * 2];
        a1 += w * sWr[c * 2 + 1];
    }
    Wfold[k * 2] = a0; Wfold[k * 2 + 1] = a1;
}

// ---------------------------------------------------------------------------
// bf16 MFMA GEMM: C[65536][2048] = A[65536][1024] @ Bt[nbase..nbase+2048)[1024]^T
// 128x128 tile, BK=64, 4 waves (2x2), 16x16x32 MFMA, global_load_lds w=16,
// XOR-swizzled LDS (pre-swizzled global source), column bias epilogue, bf16 out.
// ---------------------------------------------------------------------------
__global__ __launch_bounds__(256) void gemm_kernel(
    const ushort* __restrict__ A, const ushort* __restrict__ Bt,
    const float* __restrict__ biasv, ushort* __restrict__ C, int nbase)
{
    __shared__ __align__(16) ushort As[128 * 64];
    __shared__ __align__(16) ushort Bs[128 * 64];
    const int tid  = threadIdx.x;
    const int wid  = tid >> 6;
    const int lane = tid & 63;
    const int m0 = blockIdx.x * 128;
    const int n0 = blockIdx.y * 128;
    const int wm = (wid >> 1) * 64;
    const int wn = (wid & 1) * 64;

    // staging: lane -> (row = ch*8 + lane/8, colbyte = (lane&7)*16), source col
    // pre-swizzled by ((row&7)<<4) = ((lane>>3)<<4)
    const int r_l = lane >> 3;
    const int csw = (((lane & 7) ^ r_l) << 4) >> 1;  // in ushorts

    f32x4 acc[4][4];
    #pragma unroll
    for (int i = 0; i < 4; ++i)
        #pragma unroll
        for (int j = 0; j < 4; ++j)
            acc[i][j] = (f32x4){0.f, 0.f, 0.f, 0.f};

    const ushort* aB = A  + (size_t)(m0 + wid * 32 + r_l) * 1024 + csw;
    const ushort* bB = Bt + (size_t)(nbase + n0 + wid * 32 + r_l) * 1024 + csw;
    ushort* aL = As + wid * 2048;   // 4 chunks * 512 ushorts
    ushort* bL = Bs + wid * 2048;

    for (int k0 = 0; k0 < 1024; k0 += 64) {
        #pragma unroll
        for (int cc = 0; cc < 4; ++cc) {
            load_lds16(aB + (size_t)cc * 8 * 1024 + k0, aL + cc * 512);
            load_lds16(bB + (size_t)cc * 8 * 1024 + k0, bL + cc * 512);
        }
        __syncthreads();
        #pragma unroll
        for (int kk = 0; kk < 2; ++kk) {
            const int cb = (kk * 64 + ((lane >> 4) << 4)) ^ ((lane & 7) << 4);
            short8 af[4], bf[4];
            #pragma unroll
            for (int i = 0; i < 4; ++i) {
                af[i] = *(const short8*)((const char*)As + (wm + i * 16 + (lane & 15)) * 128 + cb);
                bf[i] = *(const short8*)((const char*)Bs + (wn + i * 16 + (lane & 15)) * 128 + cb);
            }
            #pragma unroll
            for (int i = 0; i < 4; ++i)
                #pragma unroll
                for (int j = 0; j < 4; ++j)
                    acc[i][j] = __builtin_amdgcn_mfma_f32_16x16x32_bf16(af[i], bf[j], acc[i][j], 0, 0, 0);
        }
        __syncthreads();
    }

    const int er = (lane >> 4) << 2;
    const int ec = lane & 15;
    #pragma unroll
    for (int j = 0; j < 4; ++j) {
        int col = n0 + wn + j * 16 + ec;
        float bv = biasv[nbase + col];
        #pragma unroll
        for (int i = 0; i < 4; ++i) {
            int row = m0 + wm + i * 16 + er;
            #pragma unroll
            for (int r = 0; r < 4; ++r)
                C[(size_t)(row + r) * 2048 + col] = f2bf(acc[i][j][r] + bv);
        }
    }
}

__global__ __launch_bounds__(256) void hinit_kernel(uint4* __restrict__ h) {
    size_t i = (size_t)blockIdx.x * 256 + threadIdx.x;
    h[i] = make_uint4(SENT, SENT, SENT, SENT);
}

// per edge: m[d] = U[dst][d] + V[src][d]; encoded atomicMax into h[dst]
__global__ __launch_bounds__(256) void edge_kernel(
    const ushort* __restrict__ C, const int* __restrict__ ei,
    unsigned* __restrict__ h, int E)
{
    const int e = blockIdx.x;
    const int s = ei[e];
    const int d = ei[E + e];
    const int t = threadIdx.x;
    const ushort4 u = *((const ushort4*)(C + (size_t)d * 2048) + t);
    const ushort4 v = *((const ushort4*)(C + (size_t)s * 2048 + 1024) + t);
    unsigned* hp = h + (size_t)d * 1024 + t * 4;
    atomicMax(hp + 0, enc_f(bf2f(u.x) + bf2f(v.x)));
    atomicMax(hp + 1, enc_f(bf2f(u.y) + bf2f(v.y)));
    atomicMax(hp + 2, enc_f(bf2f(u.z) + bf2f(v.z)));
    atomicMax(hp + 3, enc_f(bf2f(u.w) + bf2f(v.w)));
}

// mean-pool h (decode, SENT->0) into acc: mode 0 '=', mode 1 '+='
__global__ __launch_bounds__(256) void pool_kernel(
    const unsigned* __restrict__ h, const int* __restrict__ batch,
    float* __restrict__ acc, int N, int mode)
{
    int g = blockIdx.x >> 2;
    int d = ((blockIdx.x & 3) << 8) + threadIdx.x;
    int lo = lbound(batch, N, g);
    int hi = lbound(batch, N, g + 1);
    float s = 0.0f;
    for (int i = lo; i < hi; ++i) {
        unsigned m = h[(size_t)i * 1024 + d];
        s += (m == SENT) ? 0.0f : dec_f(m);
    }
    int cnt = hi - lo; if (cnt < 1) cnt = 1;
    float v = s / (float)cnt;
    float* p = acc + g * 1024 + d;
    if (mode) *p += v; else *p = v;
}

// out[g][o] = br[o] + sum_c (acc[g][c] + b0[c]*s0[c]+be0[c]) * Wr[c][o]
//                   + sum_k Xbar[g][k] * Wfold[k][o]
__global__ __launch_bounds__(256) void final_kernel(
    const float* __restrict__ acc, const float* __restrict__ Xbar,
    const float* __restrict__ Wfold, const float* __restrict__ Wr,
    const float* __restrict__ b0, const float* __restrict__ g0,
    const float* __restrict__ be0, const float* __restrict__ br,
    float* __restrict__ out)
{
    __shared__ float r0[256], r1[256];
    const float SF = 1.0f / sqrtf(1.0f + 1e-5f);
    int g = blockIdx.x, t = threadIdx.x;
    float p0 = 0.0f, p1 = 0.0f;
    for (int c = t; c < 1024; c += 256) {
        float a = acc[g * 1024 + c] + b0[c] * (g0[c] * SF) + be0[c];
        p0 += a * Wr[c * 2];
        p1 += a * Wr[c * 2 + 1];
        float xb = Xbar[g * 1024 + c];
        p0 += xb * Wfold[c * 2];
        p1 += xb * Wfold[c * 2 + 1];
    }
    r0[t] = p0; r1[t] = p1;
    __syncthreads();
    for (int s = 128; s > 0; s >>= 1) {
        if (t < s) { r0[t] += r0[t + s]; r1[t] += r1[t + s]; }
        __syncthreads();
    }
    if (t == 0) {
        out[g * 2 + 0] = r0[0] + br[0];
        out[g * 2 + 1] = r1[0] + br[1];
    }
}

extern "C" void kernel_launch(void* const* d_in, const int* in_sizes, int n_in,
                              void* d_out, int out_size, void* d_ws, size_t ws_size,
                              hipStream_t stream)
{
    const float* x   = (const float*)d_in[0];
    const int*   ei  = (const int*)d_in[1];
    const int* batch = (const int*)d_in[2];
    const float* W0  = (const float*)d_in[3];
    const float* b0  = (const float*)d_in[4];
    const float* g0  = (const float*)d_in[5];
    const float* be0 = (const float*)d_in[6];
    const float* W1  = (const float*)d_in[7];
    const float* g1  = (const float*)d_in[9];
    const float* b1  = (const float*)d_in[8];
    const float* be1 = (const float*)d_in[10];
    const float* W2  = (const float*)d_in[11];
    const float* b2  = (const float*)d_in[12];
    const float* g2  = (const float*)d_in[13];
    const float* be2 = (const float*)d_in[14];
    const float* Wr  = (const float*)d_in[15];
    const float* br  = (const float*)d_in[16];
    float* out = (float*)d_out;

    const int N = in_sizes[2];       // 65536
    const int E = in_sizes[1] / 2;   // 131072

    char* ws = (char*)d_ws;
    size_t off = 0;
    auto alloc = [&](size_t bytes) -> void* {
        off = (off + 255) & ~(size_t)255;
        void* p = ws + off;
        off += bytes;
        return p;
    };
    ushort*   xh    = (ushort*)alloc((size_t)N * 1024 * 2);
    ushort*   Wt    = (ushort*)alloc((size_t)4096 * 1024 * 2);
    float*    biasv = (float*)alloc(4096 * 4);
    float*    Xbar  = (float*)alloc(64 * 1024 * 4);
    float*    accb  = (float*)alloc(64 * 1024 * 4);
    float*    Wfold = (float*)alloc(1024 * 2 * 4);
    ushort*   Cbuf  = (ushort*)alloc((size_t)N * 2048 * 2);
    unsigned* hbuf  = (unsigned*)alloc((size_t)N * 1024 * 4);
    (void)ws_size; (void)n_in; (void)out_size;

    wbig_kernel<<<dim3(32, 128), 256, 0, stream>>>(W1, W2, g1, g2, Wt);
    bias_kernel<<<16, 256, 0, stream>>>(b1, g1, be1, b2, g2, be2, biasv);
    cvt_kernel<<<(N * 1024 / 8) / 256, 256, 0, stream>>>(x, xh);
    segmean_kernel<<<256, 256, 0, stream>>>(x, batch, Xbar, N);
    wfold_kernel<<<4, 256, 0, stream>>>(W0, g0, Wr, Wfold);

    for (int blk = 0; blk < 2; ++blk) {
        gemm_kernel<<<dim3(N / 128, 16), 256, 0, stream>>>(xh, Wt, biasv, Cbuf, blk * 2048);
        hinit_kernel<<<(int)((size_t)N * 1024 / 4 / 256), 256, 0, stream>>>((uint4*)hbuf);
        edge_kernel<<<E, 256, 0, stream>>>(Cbuf, ei, hbuf, E);
        pool_kernel<<<256, 256, 0, stream>>>(hbuf, batch, accb, N, blk);
    }
    final_kernel<<<64, 256, 0, stream>>>(accb, Xbar, Wfold, Wr, b0, g0, be0, br, out);
}

// Round 2
// 2726.881 us; speedup vs baseline: 1.8650x; 1.8650x over previous
//
#include <hip/hip_runtime.h>
#include <stdint.h>

// Problem constants (fixed by setup_inputs)
#define DD   1024
#define GNUM 64

typedef __attribute__((ext_vector_type(8))) short short8;
typedef __attribute__((ext_vector_type(4))) float f32x4;

__device__ __forceinline__ ushort f2bf(float f) {
    unsigned u = __float_as_uint(f);
    u += 0x7FFFu + ((u >> 16) & 1u);   // RNE
    return (ushort)(u >> 16);
}
__device__ __forceinline__ float bf2f(ushort h) {
    return __uint_as_float(((unsigned)h) << 16);
}

__device__ __forceinline__ void load_lds16(const void* g, void* l) {
    __builtin_amdgcn_global_load_lds(
        (const __attribute__((address_space(1))) unsigned*)(uintptr_t)g,
        (__attribute__((address_space(3))) unsigned*)(uint32_t)(uintptr_t)l,
        16, 0, 0);
}

__device__ __forceinline__ int lbound(const int* a, int n, int v) {
    int lo = 0, hi = n;
    while (lo < hi) { int m = (lo + hi) >> 1; if (a[m] < v) lo = m + 1; else hi = m; }
    return lo;
}

// ---------------------------------------------------------------------------
// Build WbigT [4096][1024] bf16 (transposed weights, BN scale folded in).
// ---------------------------------------------------------------------------
__global__ __launch_bounds__(256) void wbig_kernel(
    const float* __restrict__ W1, const float* __restrict__ W2,
    const float* __restrict__ g1, const float* __restrict__ g2,
    ushort* __restrict__ Wt)
{
    __shared__ float tile[32][33];
    const float SF = 1.0f / sqrtf(1.0f + 1e-5f);
    int k0 = blockIdx.x * 32, c0 = blockIdx.y * 32;
    int tx = threadIdx.x & 31, ty = threadIdx.x >> 5;  // ty 0..7
    int sec = c0 >> 10;
    int cl = (c0 & 1023) + tx;
    const float* W  = (sec < 2) ? W1 : W2;
    const float* gv = (sec < 2) ? g1 : g2;
    bool isU = (sec & 1) == 0;
    float sc = gv[cl] * SF;
    #pragma unroll
    for (int j = 0; j < 4; ++j) {
        int k = k0 + ty + j * 8;
        float v = isU ? (W[(size_t)k * 1024 + cl] - W[(size_t)(k + 1024) * 1024 + cl]) * sc
                      : W[(size_t)(k + 1024) * 1024 + cl] * sc;
        tile[ty + j * 8][tx] = v;
    }
    __syncthreads();
    #pragma unroll
    for (int j = 0; j < 4; ++j) {
        int cc = ty + j * 8;
        Wt[(size_t)(c0 + cc) * 1024 + k0 + tx] = f2bf(tile[tx][cc]);
    }
}

__global__ __launch_bounds__(256) void bias_kernel(
    const float* __restrict__ b1, const float* __restrict__ g1, const float* __restrict__ be1,
    const float* __restrict__ b2, const float* __restrict__ g2, const float* __restrict__ be2,
    float* __restrict__ biasv)
{
    const float SF = 1.0f / sqrtf(1.0f + 1e-5f);
    int c = blockIdx.x * 256 + threadIdx.x;  // 0..4095
    int sec = c >> 10, cl = c & 1023;
    float v = 0.0f;
    if (sec == 0) v = b1[cl] * (g1[cl] * SF) + be1[cl];
    else if (sec == 2) v = b2[cl] * (g2[cl] * SF) + be2[cl];
    biasv[c] = v;
}

__global__ __launch_bounds__(256) void cvt_kernel(
    const float* __restrict__ x, ushort* __restrict__ xh)
{
    size_t i = ((size_t)blockIdx.x * 256 + threadIdx.x) * 8;
    const float4 a = *(const float4*)(x + i);
    const float4 b = *(const float4*)(x + i + 4);
    ushort4 lo = make_ushort4(f2bf(a.x), f2bf(a.y), f2bf(a.z), f2bf(a.w));
    ushort4 hi = make_ushort4(f2bf(b.x), f2bf(b.y), f2bf(b.z), f2bf(b.w));
    *(ushort4*)(xh + i) = lo;
    *(ushort4*)(xh + i + 4) = hi;
}

// per-graph mean of x  -> Xbar [64][1024]  (deterministic: contiguous ranges)
__global__ __launch_bounds__(256) void segmean_kernel(
    const float* __restrict__ x, const int* __restrict__ batch,
    float* __restrict__ Xbar, int N)
{
    int g = blockIdx.x >> 2;
    int d = ((blockIdx.x & 3) << 8) + threadIdx.x;
    int lo = lbound(batch, N, g);
    int hi = lbound(batch, N, g + 1);
    float s = 0.0f;
    for (int i = lo; i < hi; ++i) s += x[(size_t)i * 1024 + d];
    int cnt = hi - lo; if (cnt < 1) cnt = 1;
    Xbar[g * 1024 + d] = s / (float)cnt;
}

// Wfold[k][o] = sum_c W0[k][c]*s0[c]*Wr[c][o]   (block-0 collapsed into final)
__global__ __launch_bounds__(256) void wfold_kernel(
    const float* __restrict__ W0, const float* __restrict__ g0,
    const float* __restrict__ Wr, float* __restrict__ Wfold)
{
    __shared__ float sWr[2048];
    __shared__ float sS[1024];
    const float SF = 1.0f / sqrtf(1.0f + 1e-5f);
    for (int i = threadIdx.x; i < 2048; i += 256) sWr[i] = Wr[i];
    for (int i = threadIdx.x; i < 1024; i += 256) sS[i] = g0[i] * SF;
    __syncthreads();
    int k = blockIdx.x * 256 + threadIdx.x;  // 0..1023
    const float* row = W0 + (size_t)k * 1024;
    float a0 = 0.0f, a1 = 0.0f;
    for (int c = 0; c < 1024; ++c) {
        float w = row[c] * sS[c];
        a0 += w * sWr[c * 2];
        a1 += w * sWr[c * 2 + 1];
    }
    Wfold[k * 2] = a0; Wfold[k * 2 + 1] = a1;
}

// ---------------------------------------------------------------------------
// bf16 MFMA GEMM: C[65536][2048] = A[65536][1024] @ Bt[nbase..nbase+2048)[1024]^T
// ---------------------------------------------------------------------------
__global__ __launch_bounds__(256) void gemm_kernel(
    const ushort* __restrict__ A, const ushort* __restrict__ Bt,
    const float* __restrict__ biasv, ushort* __restrict__ C, int nbase)
{
    __shared__ __align__(16) ushort As[128 * 64];
    __shared__ __align__(16) ushort Bs[128 * 64];
    const int tid  = threadIdx.x;
    const int wid  = tid >> 6;
    const int lane = tid & 63;
    const int m0 = blockIdx.x * 128;
    const int n0 = blockIdx.y * 128;
    const int wm = (wid >> 1) * 64;
    const int wn = (wid & 1) * 64;

    const int r_l = lane >> 3;
    const int csw = (((lane & 7) ^ r_l) << 4) >> 1;  // in ushorts

    f32x4 acc[4][4];
    #pragma unroll
    for (int i = 0; i < 4; ++i)
        #pragma unroll
        for (int j = 0; j < 4; ++j)
            acc[i][j] = (f32x4){0.f, 0.f, 0.f, 0.f};

    const ushort* aB = A  + (size_t)(m0 + wid * 32 + r_l) * 1024 + csw;
    const ushort* bB = Bt + (size_t)(nbase + n0 + wid * 32 + r_l) * 1024 + csw;
    ushort* aL = As + wid * 2048;
    ushort* bL = Bs + wid * 2048;

    for (int k0 = 0; k0 < 1024; k0 += 64) {
        #pragma unroll
        for (int cc = 0; cc < 4; ++cc) {
            load_lds16(aB + (size_t)cc * 8 * 1024 + k0, aL + cc * 512);
            load_lds16(bB + (size_t)cc * 8 * 1024 + k0, bL + cc * 512);
        }
        __syncthreads();
        #pragma unroll
        for (int kk = 0; kk < 2; ++kk) {
            const int cb = (kk * 64 + ((lane >> 4) << 4)) ^ ((lane & 7) << 4);
            short8 af[4], bf[4];
            #pragma unroll
            for (int i = 0; i < 4; ++i) {
                af[i] = *(const short8*)((const char*)As + (wm + i * 16 + (lane & 15)) * 128 + cb);
                bf[i] = *(const short8*)((const char*)Bs + (wn + i * 16 + (lane & 15)) * 128 + cb);
            }
            #pragma unroll
            for (int i = 0; i < 4; ++i)
                #pragma unroll
                for (int j = 0; j < 4; ++j)
                    acc[i][j] = __builtin_amdgcn_mfma_f32_16x16x32_bf16(af[i], bf[j], acc[i][j], 0, 0, 0);
        }
        __syncthreads();
    }

    const int er = (lane >> 4) << 2;
    const int ec = lane & 15;
    #pragma unroll
    for (int j = 0; j < 4; ++j) {
        int col = n0 + wn + j * 16 + ec;
        float bv = biasv[nbase + col];
        #pragma unroll
        for (int i = 0; i < 4; ++i) {
            int row = m0 + wm + i * 16 + er;
            #pragma unroll
            for (int r = 0; r < 4; ++r)
                C[(size_t)(row + r) * 2048 + col] = f2bf(acc[i][j][r] + bv);
        }
    }
}

// ---------------------------------------------------------------------------
// CSR build: deg -> exclusive scan -> scatter (src stored per dst bucket).
// Intra-bucket order is nondeterministic but fp max is order-invariant.
// ---------------------------------------------------------------------------
__global__ __launch_bounds__(256) void zero_kernel(int* __restrict__ p, int n) {
    int i = blockIdx.x * 256 + threadIdx.x;
    if (i < n) p[i] = 0;
}

__global__ __launch_bounds__(256) void degcount_kernel(
    const int* __restrict__ ei, int* __restrict__ deg, int E)
{
    int e = blockIdx.x * 256 + threadIdx.x;
    if (e < E) atomicAdd(&deg[ei[E + e]], 1);
}

__global__ __launch_bounds__(1024) void scan_kernel(
    const int* __restrict__ deg, int* __restrict__ rowptr,
    int* __restrict__ cursor, int N, int E)
{
    __shared__ int part[1024];
    int t = threadIdx.x;
    int chunk = N / 1024;
    int base = t * chunk;
    int s = 0;
    for (int i = 0; i < chunk; ++i) s += deg[base + i];
    part[t] = s;
    __syncthreads();
    for (int ofs = 1; ofs < 1024; ofs <<= 1) {
        int v = (t >= ofs) ? part[t - ofs] : 0;
        __syncthreads();
        part[t] += v;
        __syncthreads();
    }
    int run = (t == 0) ? 0 : part[t - 1];  // exclusive prefix
    for (int i = 0; i < chunk; ++i) {
        rowptr[base + i] = run;
        cursor[base + i] = run;
        run += deg[base + i];
    }
    if (t == 1023) rowptr[N] = E;
}

__global__ __launch_bounds__(256) void scatter_kernel(
    const int* __restrict__ ei, int* __restrict__ cursor,
    int* __restrict__ col, int E)
{
    int e = blockIdx.x * 256 + threadIdx.x;
    if (e < E) {
        int d = ei[E + e];
        int pos = atomicAdd(&cursor[d], 1);
        col[pos] = ei[e];
    }
}

// ---------------------------------------------------------------------------
// gather-max: one wave per node. h[i] = deg>0 ? U[i] + max_src V[src] : 0
// U = C[:, 0:1024), V = C[:, 1024:2048)
// ---------------------------------------------------------------------------
__global__ __launch_bounds__(256) void gathermax_kernel(
    const ushort* __restrict__ C, const int* __restrict__ rowptr,
    const int* __restrict__ col, float* __restrict__ h)
{
    const int wave = threadIdx.x >> 6;
    const int lane = threadIdx.x & 63;
    const int node = blockIdx.x * 4 + wave;
    const int lo = rowptr[node], hi = rowptr[node + 1];

    float vmax[16];
    #pragma unroll
    for (int i = 0; i < 16; ++i) vmax[i] = -3.4e38f;

    for (int j = lo; j < hi; ++j) {
        const int s = col[j];
        const ushort* vp = C + (size_t)s * 2048 + 1024 + lane * 8;
        short8 v0 = *(const short8*)vp;
        short8 v1 = *(const short8*)(vp + 512);
        #pragma unroll
        for (int q = 0; q < 8; ++q) {
            vmax[q]     = fmaxf(vmax[q],     bf2f((ushort)v0[q]));
            vmax[8 + q] = fmaxf(vmax[8 + q], bf2f((ushort)v1[q]));
        }
    }

    const ushort* up = C + (size_t)node * 2048 + lane * 8;
    short8 u0 = *(const short8*)up;
    short8 u1 = *(const short8*)(up + 512);
    const bool has = hi > lo;

    float o[16];
    #pragma unroll
    for (int q = 0; q < 8; ++q) {
        o[q]     = has ? vmax[q]     + bf2f((ushort)u0[q]) : 0.0f;
        o[8 + q] = has ? vmax[8 + q] + bf2f((ushort)u1[q]) : 0.0f;
    }
    float* hp = h + (size_t)node * 1024 + lane * 8;
    *(float4*)(hp)       = make_float4(o[0], o[1], o[2], o[3]);
    *(float4*)(hp + 4)   = make_float4(o[4], o[5], o[6], o[7]);
    *(float4*)(hp + 512) = make_float4(o[8], o[9], o[10], o[11]);
    *(float4*)(hp + 516) = make_float4(o[12], o[13], o[14], o[15]);
}

// mean-pool h into acc: mode 0 '=', mode 1 '+='
__global__ __launch_bounds__(256) void pool_kernel(
    const float* __restrict__ h, const int* __restrict__ batch,
    float* __restrict__ acc, int N, int mode)
{
    int g = blockIdx.x >> 2;
    int d = ((blockIdx.x & 3) << 8) + threadIdx.x;
    int lo = lbound(batch, N, g);
    int hi = lbound(batch, N, g + 1);
    float s = 0.0f;
    for (int i = lo; i < hi; ++i) s += h[(size_t)i * 1024 + d];
    int cnt = hi - lo; if (cnt < 1) cnt = 1;
    float v = s / (float)cnt;
    float* p = acc + g * 1024 + d;
    if (mode) *p += v; else *p = v;
}

__global__ __launch_bounds__(256) void final_kernel(
    const float* __restrict__ acc, const float* __restrict__ Xbar,
    const float* __restrict__ Wfold, const float* __restrict__ Wr,
    const float* __restrict__ b0, const float* __restrict__ g0,
    const float* __restrict__ be0, const float* __restrict__ br,
    float* __restrict__ out)
{
    __shared__ float r0[256], r1[256];
    const float SF = 1.0f / sqrtf(1.0f + 1e-5f);
    int g = blockIdx.x, t = threadIdx.x;
    float p0 = 0.0f, p1 = 0.0f;
    for (int c = t; c < 1024; c += 256) {
        float a = acc[g * 1024 + c] + b0[c] * (g0[c] * SF) + be0[c];
        p0 += a * Wr[c * 2];
        p1 += a * Wr[c * 2 + 1];
        float xb = Xbar[g * 1024 + c];
        p0 += xb * Wfold[c * 2];
        p1 += xb * Wfold[c * 2 + 1];
    }
    r0[t] = p0; r1[t] = p1;
    __syncthreads();
    for (int s = 128; s > 0; s >>= 1) {
        if (t < s) { r0[t] += r0[t + s]; r1[t] += r1[t + s]; }
        __syncthreads();
    }
    if (t == 0) {
        out[g * 2 + 0] = r0[0] + br[0];
        out[g * 2 + 1] = r1[0] + br[1];
    }
}

extern "C" void kernel_launch(void* const* d_in, const int* in_sizes, int n_in,
                              void* d_out, int out_size, void* d_ws, size_t ws_size,
                              hipStream_t stream)
{
    const float* x   = (const float*)d_in[0];
    const int*   ei  = (const int*)d_in[1];
    const int* batch = (const int*)d_in[2];
    const float* W0  = (const float*)d_in[3];
    const float* b0  = (const float*)d_in[4];
    const float* g0  = (const float*)d_in[5];
    const float* be0 = (const float*)d_in[6];
    const float* W1  = (const float*)d_in[7];
    const float* b1  = (const float*)d_in[8];
    const float* g1  = (const float*)d_in[9];
    const float* be1 = (const float*)d_in[10];
    const float* W2  = (const float*)d_in[11];
    const float* b2  = (const float*)d_in[12];
    const float* g2  = (const float*)d_in[13];
    const float* be2 = (const float*)d_in[14];
    const float* Wr  = (const float*)d_in[15];
    const float* br  = (const float*)d_in[16];
    float* out = (float*)d_out;

    const int N = in_sizes[2];       // 65536
    const int E = in_sizes[1] / 2;   // 131072

    char* ws = (char*)d_ws;
    size_t off = 0;
    auto alloc = [&](size_t bytes) -> void* {
        off = (off + 255) & ~(size_t)255;
        void* p = ws + off;
        off += bytes;
        return p;
    };
    ushort*   xh    = (ushort*)alloc((size_t)N * 1024 * 2);
    ushort*   Wt    = (ushort*)alloc((size_t)4096 * 1024 * 2);
    float*    biasv = (float*)alloc(4096 * 4);
    float*    Xbar  = (float*)alloc(64 * 1024 * 4);
    float*    accb  = (float*)alloc(64 * 1024 * 4);
    float*    Wfold = (float*)alloc(1024 * 2 * 4);
    ushort*   Cbuf  = (ushort*)alloc((size_t)N * 2048 * 2);
    float*    hbuf  = (float*)alloc((size_t)N * 1024 * 4);
    int*      deg    = (int*)alloc((size_t)N * 4);
    int*      rowptr = (int*)alloc(((size_t)N + 1) * 4);
    int*      cursor = (int*)alloc((size_t)N * 4);
    int*      colb   = (int*)alloc((size_t)E * 4);
    (void)ws_size; (void)n_in; (void)out_size;

    // --- weight prep + x conversion + block-0 folds ---
    wbig_kernel<<<dim3(32, 128), 256, 0, stream>>>(W1, W2, g1, g2, Wt);
    bias_kernel<<<16, 256, 0, stream>>>(b1, g1, be1, b2, g2, be2, biasv);
    cvt_kernel<<<(N * 1024 / 8) / 256, 256, 0, stream>>>(x, xh);
    segmean_kernel<<<256, 256, 0, stream>>>(x, batch, Xbar, N);
    wfold_kernel<<<4, 256, 0, stream>>>(W0, g0, Wr, Wfold);

    // --- CSR by dst (once; shared by both EdgeConv blocks) ---
    zero_kernel<<<(N + 255) / 256, 256, 0, stream>>>(deg, N);
    degcount_kernel<<<(E + 255) / 256, 256, 0, stream>>>(ei, deg, E);
    scan_kernel<<<1, 1024, 0, stream>>>(deg, rowptr, cursor, N, E);
    scatter_kernel<<<(E + 255) / 256, 256, 0, stream>>>(ei, cursor, colb, E);

    for (int blk = 0; blk < 2; ++blk) {
        gemm_kernel<<<dim3(N / 128, 16), 256, 0, stream>>>(xh, Wt, biasv, Cbuf, blk * 2048);
        gathermax_kernel<<<N / 4, 256, 0, stream>>>(Cbuf, rowptr, colb, hbuf);
        pool_kernel<<<256, 256, 0, stream>>>(hbuf, batch, accb, N, blk);
    }
    final_kernel<<<64, 256, 0, stream>>>(accb, Xbar, Wfold, Wr, b0, g0, be0, br, out);
}

// Round 3
// 1687.203 us; speedup vs baseline: 3.0142x; 1.6162x over previous
//
#include <hip/hip_runtime.h>
#include <stdint.h>

#define DD   1024
#define GNUM 64

typedef __attribute__((ext_vector_type(8))) short short8;
typedef __attribute__((ext_vector_type(4))) float f32x4;

__device__ __forceinline__ ushort f2bf(float f) {
    unsigned u = __float_as_uint(f);
    u += 0x7FFFu + ((u >> 16) & 1u);   // RNE
    return (ushort)(u >> 16);
}
__device__ __forceinline__ float bf2f(ushort h) {
    return __uint_as_float(((unsigned)h) << 16);
}

__device__ __forceinline__ void load_lds16(const void* g, void* l) {
    __builtin_amdgcn_global_load_lds(
        (const __attribute__((address_space(1))) unsigned*)(uintptr_t)g,
        (__attribute__((address_space(3))) unsigned*)(uint32_t)(uintptr_t)l,
        16, 0, 0);
}

__device__ __forceinline__ int lbound(const int* a, int n, int v) {
    int lo = 0, hi = n;
    while (lo < hi) { int m = (lo + hi) >> 1; if (a[m] < v) lo = m + 1; else hi = m; }
    return lo;
}

// ---------------------------------------------------------------------------
// Build WbigT [4096][1024] bf16 (transposed weights, BN scale folded in).
// ---------------------------------------------------------------------------
__global__ __launch_bounds__(256) void wbig_kernel(
    const float* __restrict__ W1, const float* __restrict__ W2,
    const float* __restrict__ g1, const float* __restrict__ g2,
    ushort* __restrict__ Wt)
{
    __shared__ float tile[32][33];
    const float SF = 1.0f / sqrtf(1.0f + 1e-5f);
    int k0 = blockIdx.x * 32, c0 = blockIdx.y * 32;
    int tx = threadIdx.x & 31, ty = threadIdx.x >> 5;
    int sec = c0 >> 10;
    int cl = (c0 & 1023) + tx;
    const float* W  = (sec < 2) ? W1 : W2;
    const float* gv = (sec < 2) ? g1 : g2;
    bool isU = (sec & 1) == 0;
    float sc = gv[cl] * SF;
    #pragma unroll
    for (int j = 0; j < 4; ++j) {
        int k = k0 + ty + j * 8;
        float v = isU ? (W[(size_t)k * 1024 + cl] - W[(size_t)(k + 1024) * 1024 + cl]) * sc
                      : W[(size_t)(k + 1024) * 1024 + cl] * sc;
        tile[ty + j * 8][tx] = v;
    }
    __syncthreads();
    #pragma unroll
    for (int j = 0; j < 4; ++j) {
        int cc = ty + j * 8;
        Wt[(size_t)(c0 + cc) * 1024 + k0 + tx] = f2bf(tile[tx][cc]);
    }
}

__global__ __launch_bounds__(256) void bias_kernel(
    const float* __restrict__ b1, const float* __restrict__ g1, const float* __restrict__ be1,
    const float* __restrict__ b2, const float* __restrict__ g2, const float* __restrict__ be2,
    float* __restrict__ biasv)
{
    const float SF = 1.0f / sqrtf(1.0f + 1e-5f);
    int c = blockIdx.x * 256 + threadIdx.x;
    int sec = c >> 10, cl = c & 1023;
    float v = 0.0f;
    if (sec == 0) v = b1[cl] * (g1[cl] * SF) + be1[cl];
    else if (sec == 2) v = b2[cl] * (g2[cl] * SF) + be2[cl];
    biasv[c] = v;
}

__global__ __launch_bounds__(256) void cvt_kernel(
    const float* __restrict__ x, ushort* __restrict__ xh)
{
    size_t i = ((size_t)blockIdx.x * 256 + threadIdx.x) * 8;
    const float4 a = *(const float4*)(x + i);
    const float4 b = *(const float4*)(x + i + 4);
    ushort4 lo = make_ushort4(f2bf(a.x), f2bf(a.y), f2bf(a.z), f2bf(a.w));
    ushort4 hi = make_ushort4(f2bf(b.x), f2bf(b.y), f2bf(b.z), f2bf(b.w));
    *(ushort4*)(xh + i) = lo;
    *(ushort4*)(xh + i + 4) = hi;
}

__global__ __launch_bounds__(256) void segmean_kernel(
    const float* __restrict__ x, const int* __restrict__ batch,
    float* __restrict__ Xbar, int N)
{
    int g = blockIdx.x >> 2;
    int d = ((blockIdx.x & 3) << 8) + threadIdx.x;
    int lo = lbound(batch, N, g);
    int hi = lbound(batch, N, g + 1);
    float s = 0.0f;
    for (int i = lo; i < hi; ++i) s += x[(size_t)i * 1024 + d];
    int cnt = hi - lo; if (cnt < 1) cnt = 1;
    Xbar[g * 1024 + d] = s / (float)cnt;
}

// Wfold[k][o] = sum_c W0[k][c]*s0[c]*Wr[c][o]  -- one block per k, coalesced
__global__ __launch_bounds__(256) void wfold_kernel(
    const float* __restrict__ W0, const float* __restrict__ g0,
    const float* __restrict__ Wr, float* __restrict__ Wfold)
{
    __shared__ float r0s[256], r1s[256];
    const float SF = 1.0f / sqrtf(1.0f + 1e-5f);
    int k = blockIdx.x, t = threadIdx.x;
    float a0 = 0.0f, a1 = 0.0f;
    for (int c = t; c < 1024; c += 256) {
        float w = W0[(size_t)k * 1024 + c] * (g0[c] * SF);
        a0 += w * Wr[c * 2];
        a1 += w * Wr[c * 2 + 1];
    }
    r0s[t] = a0; r1s[t] = a1;
    __syncthreads();
    for (int s = 128; s > 0; s >>= 1) {
        if (t < s) { r0s[t] += r0s[t + s]; r1s[t] += r1s[t + s]; }
        __syncthreads();
    }
    if (t == 0) { Wfold[k * 2] = r0s[0]; Wfold[k * 2 + 1] = r1s[0]; }
}

// ---------------------------------------------------------------------------
// 256x256-tile 8-phase bf16 GEMM (T2 swizzle + T3/T4 counted vmcnt + T5).
// C[65536][2048] = A[65536][1024] @ Bt[nbase+n][k]^T, bias epilogue, bf16 out.
// 512 thr = 8 waves (2 Mx4 N); per-wave 128x64 out; BK=64; NT=16 K-tiles.
// LDS 128KB: A[2buf][2half][128r][64k], B likewise (ushort).
// Schedule: tile t computes from buf[t&1]; P1/P2 stage A0/A1(t+1) into the
// other buffer; P3/P4 stage B0/B1(t+2) into just-dead regions of this buffer
// (B halves fully read by end of P2). Boundary waits vmcnt(4) -> exactly
// tile t+1 confirmed, B(t+2) (4 loads) still in flight. Last boundary: vmcnt(0).
// ---------------------------------------------------------------------------
__global__ __launch_bounds__(512, 2) void gemm8_kernel(
    const ushort* __restrict__ A, const ushort* __restrict__ Bt,
    const float* __restrict__ biasv, ushort* __restrict__ C, int nbase)
{
    __shared__ __align__(16) ushort SM[65536];   // 128 KiB
    const int tid  = threadIdx.x;
    const int w    = tid >> 6;
    const int lane = tid & 63;
    const int wr = w >> 2;        // 0..1  (M)
    const int wc = w & 3;         // 0..3  (N)

    // bijective XCD-chunked, n-fastest block order (nwg=2048 % 8 == 0)
    const int bx  = blockIdx.x;
    const int swz = (bx & 7) * 256 + (bx >> 3);
    const int m0 = (swz >> 3) * 256;
    const int n0 = (swz & 7) * 256;

    // staging: per wave, 8 rows per issue; source col pre-swizzled (rule 21)
    const int srow = lane >> 3;                    // row&7
    const int csw  = ((lane & 7) ^ srow) << 3;     // ushort offset of 16B chunk

    auto stA = [&](int t, int h) {
        if (t >= 16) return;
        const int c = t & 1;
        const ushort* s = A + (size_t)(m0 + h * 128 + w * 8 + srow) * 1024 + t * 64 + csw;
        ushort* d = SM + c * 16384 + h * 8192 + w * 512;
        load_lds16(s, d);
        load_lds16(s + (size_t)64 * 1024, d + 4096);
    };
    auto stB = [&](int t, int h) {
        if (t >= 16) return;
        const int c = t & 1;
        const ushort* s = Bt + (size_t)(nbase + n0 + h * 128 + w * 8 + srow) * 1024 + t * 64 + csw;
        ushort* d = SM + 32768 + c * 16384 + h * 8192 + w * 512;
        load_lds16(s, d);
        load_lds16(s + (size_t)64 * 1024, d + 4096);
    };

    const int cbk0 = ((lane >> 4) << 4);
    const int cbx  = (lane & 7) << 4;
    auto rdA = [&](int c, int i, int kk) -> short8 {
        int row = i * 16 + (lane & 15);
        int cb  = (kk * 64 + cbk0) ^ cbx;
        return *(const short8*)((const char*)SM + (c * 16384 + wr * 8192) * 2 + row * 128 + cb);
    };
    auto rdB = [&](int c, int j, int kk) -> short8 {
        int row = (wc & 1) * 64 + j * 16 + (lane & 15);
        int cb  = (kk * 64 + cbk0) ^ cbx;
        return *(const short8*)((const char*)SM + 65536 + (c * 16384 + (wc >> 1) * 8192) * 2 + row * 128 + cb);
    };

    f32x4 acc[8][4];
    #pragma unroll
    for (int i = 0; i < 8; ++i)
        #pragma unroll
        for (int j = 0; j < 4; ++j)
            acc[i][j] = (f32x4){0.f, 0.f, 0.f, 0.f};

    short8 afr[4][2], bfr[4][2];

    // prologue: tile0 complete + B halves of tile1; confirm tile0, keep 4 in flight
    stA(0, 0); stA(0, 1); stB(0, 0); stB(0, 1); stB(1, 0); stB(1, 1);
    asm volatile("s_waitcnt vmcnt(4)" ::: "memory");
    __builtin_amdgcn_s_barrier();

    for (int t = 0; t < 16; ++t) {
        const int c = t & 1;
        // ---- P1: read A(i0-3), B(j0-1); stage A0(t+1); mfma q(0,0)
        #pragma unroll
        for (int i = 0; i < 4; ++i) { afr[i][0] = rdA(c, i, 0); afr[i][1] = rdA(c, i, 1); }
        #pragma unroll
        for (int j = 0; j < 2; ++j) { bfr[j][0] = rdB(c, j, 0); bfr[j][1] = rdB(c, j, 1); }
        stA(t + 1, 0);
        __builtin_amdgcn_s_barrier();
        __builtin_amdgcn_s_setprio(1);
        #pragma unroll
        for (int i = 0; i < 4; ++i)
            #pragma unroll
            for (int j = 0; j < 2; ++j) {
                acc[i][j] = __builtin_amdgcn_mfma_f32_16x16x32_bf16(afr[i][0], bfr[j][0], acc[i][j], 0, 0, 0);
                acc[i][j] = __builtin_amdgcn_mfma_f32_16x16x32_bf16(afr[i][1], bfr[j][1], acc[i][j], 0, 0, 0);
            }
        __builtin_amdgcn_s_setprio(0);
        __builtin_amdgcn_s_barrier();

        // ---- P2: read B(j2-3); stage A1(t+1); mfma q(0,1)
        #pragma unroll
        for (int j = 2; j < 4; ++j) { bfr[j][0] = rdB(c, j, 0); bfr[j][1] = rdB(c, j, 1); }
        stA(t + 1, 1);
        __builtin_amdgcn_s_barrier();
        __builtin_amdgcn_s_setprio(1);
        #pragma unroll
        for (int i = 0; i < 4; ++i)
            #pragma unroll
            for (int j = 2; j < 4; ++j) {
                acc[i][j] = __builtin_amdgcn_mfma_f32_16x16x32_bf16(afr[i][0], bfr[j][0], acc[i][j], 0, 0, 0);
                acc[i][j] = __builtin_amdgcn_mfma_f32_16x16x32_bf16(afr[i][1], bfr[j][1], acc[i][j], 0, 0, 0);
            }
        __builtin_amdgcn_s_setprio(0);
        __builtin_amdgcn_s_barrier();

        // ---- P3: read A(i4-7); stage B0(t+2); mfma q(1,1)
        #pragma unroll
        for (int i = 0; i < 4; ++i) { afr[i][0] = rdA(c, i + 4, 0); afr[i][1] = rdA(c, i + 4, 1); }
        stB(t + 2, 0);
        __builtin_amdgcn_s_barrier();
        __builtin_amdgcn_s_setprio(1);
        #pragma unroll
        for (int i = 0; i < 4; ++i)
            #pragma unroll
            for (int j = 2; j < 4; ++j) {
                acc[i + 4][j] = __builtin_amdgcn_mfma_f32_16x16x32_bf16(afr[i][0], bfr[j][0], acc[i + 4][j], 0, 0, 0);
                acc[i + 4][j] = __builtin_amdgcn_mfma_f32_16x16x32_bf16(afr[i][1], bfr[j][1], acc[i + 4][j], 0, 0, 0);
            }
        __builtin_amdgcn_s_setprio(0);
        __builtin_amdgcn_s_barrier();

        // ---- P4: stage B1(t+2); mfma q(1,0); boundary wait
        stB(t + 2, 1);
        __builtin_amdgcn_s_barrier();
        __builtin_amdgcn_s_setprio(1);
        #pragma unroll
        for (int i = 0; i < 4; ++i)
            #pragma unroll
            for (int j = 0; j < 2; ++j) {
                acc[i + 4][j] = __builtin_amdgcn_mfma_f32_16x16x32_bf16(afr[i][0], bfr[j][0], acc[i + 4][j], 0, 0, 0);
                acc[i + 4][j] = __builtin_amdgcn_mfma_f32_16x16x32_bf16(afr[i][1], bfr[j][1], acc[i + 4][j], 0, 0, 0);
            }
        __builtin_amdgcn_s_setprio(0);
        if (t < 15) {
            if (t < 14) asm volatile("s_waitcnt vmcnt(4)" ::: "memory");
            else        asm volatile("s_waitcnt vmcnt(0)" ::: "memory");
            __builtin_amdgcn_s_barrier();
        }
    }

    // epilogue
    const int er = (lane >> 4) << 2;
    const int ec = lane & 15;
    #pragma unroll
    for (int j = 0; j < 4; ++j) {
        int col = n0 + wc * 64 + j * 16 + ec;
        float bv = biasv[nbase + col];
        #pragma unroll
        for (int i = 0; i < 8; ++i) {
            int row = m0 + wr * 128 + i * 16 + er;
            #pragma unroll
            for (int r = 0; r < 4; ++r)
                C[(size_t)(row + r) * 2048 + col] = f2bf(acc[i][j][r] + bv);
        }
    }
}

// ---------------------------------------------------------------------------
// CSR build (shared by both EdgeConv blocks)
// ---------------------------------------------------------------------------
__global__ __launch_bounds__(256) void zero_kernel(int* __restrict__ p, int n) {
    int i = blockIdx.x * 256 + threadIdx.x;
    if (i < n) p[i] = 0;
}

__global__ __launch_bounds__(256) void degcount_kernel(
    const int* __restrict__ ei, int* __restrict__ deg, int E)
{
    int e = blockIdx.x * 256 + threadIdx.x;
    if (e < E) atomicAdd(&deg[ei[E + e]], 1);
}

__global__ __launch_bounds__(1024) void scan_kernel(
    const int* __restrict__ deg, int* __restrict__ rowptr,
    int* __restrict__ cursor, int N, int E)
{
    __shared__ int part[1024];
    int t = threadIdx.x;
    int chunk = N / 1024;
    int base = t * chunk;
    int s = 0;
    for (int i = 0; i < chunk; ++i) s += deg[base + i];
    part[t] = s;
    __syncthreads();
    for (int ofs = 1; ofs < 1024; ofs <<= 1) {
        int v = (t >= ofs) ? part[t - ofs] : 0;
        __syncthreads();
        part[t] += v;
        __syncthreads();
    }
    int run = (t == 0) ? 0 : part[t - 1];
    for (int i = 0; i < chunk; ++i) {
        rowptr[base + i] = run;
        cursor[base + i] = run;
        run += deg[base + i];
    }
    if (t == 1023) rowptr[N] = E;
}

__global__ __launch_bounds__(256) void scatter_kernel(
    const int* __restrict__ ei, int* __restrict__ cursor,
    int* __restrict__ col, int E)
{
    int e = blockIdx.x * 256 + threadIdx.x;
    if (e < E) {
        int d = ei[E + e];
        int pos = atomicAdd(&cursor[d], 1);
        col[pos] = ei[e];
    }
}

// ---------------------------------------------------------------------------
// Fused gather-max + pool partials. Block = (graph, node-subrange, d-chunk).
// partial[g*8+sub][d] = sum over nodes of (deg>0 ? U[node][d]+max_src V[src][d] : 0)
// Deterministic (fixed-order sums; fp max order-invariant).
// ---------------------------------------------------------------------------
__global__ __launch_bounds__(256) void edgepool_kernel(
    const ushort* __restrict__ C, const int* __restrict__ rowptr,
    const int* __restrict__ colb, const int* __restrict__ batch,
    float* __restrict__ partial, int N)
{
    const int b = blockIdx.x;            // 64g * 8sub * 4chunk = 2048
    const int g = b >> 5;
    const int sub = (b >> 2) & 7;
    const int d = ((b & 3) << 8) + threadIdx.x;

    const int glo = lbound(batch, N, g);
    const int ghi = lbound(batch, N, g + 1);
    const int len = ghi - glo;
    const int s0 = glo + (len * sub) / 8;
    const int s1 = glo + (len * (sub + 1)) / 8;

    float sum = 0.0f;
    int lo = (s0 < s1) ? rowptr[s0] : 0;
    for (int node = s0; node < s1; ++node) {
        int hi = rowptr[node + 1];
        float vmax = -3.4e38f;
        for (int j = lo; j < hi; ++j) {
            int src = colb[j];
            vmax = fmaxf(vmax, bf2f(C[(size_t)src * 2048 + 1024 + d]));
        }
        float u = bf2f(C[(size_t)node * 2048 + d]);
        sum += (hi > lo) ? (u + vmax) : 0.0f;
        lo = hi;
    }
    partial[(size_t)(g * 8 + sub) * 1024 + d] = sum;
}

// reduce partials -> per-graph mean; mode 0 '=', mode 1 '+='
__global__ __launch_bounds__(256) void poolreduce_kernel(
    const float* __restrict__ partial, const int* __restrict__ batch,
    float* __restrict__ acc, int N, int mode)
{
    int g = blockIdx.x >> 2;
    int d = ((blockIdx.x & 3) << 8) + threadIdx.x;
    int glo = lbound(batch, N, g);
    int ghi = lbound(batch, N, g + 1);
    float s = 0.0f;
    #pragma unroll
    for (int k = 0; k < 8; ++k) s += partial[(size_t)(g * 8 + k) * 1024 + d];
    int cnt = ghi - glo; if (cnt < 1) cnt = 1;
    float v = s / (float)cnt;
    float* p = acc + g * 1024 + d;
    if (mode) *p += v; else *p = v;
}

__global__ __launch_bounds__(256) void final_kernel(
    const float* __restrict__ acc, const float* __restrict__ Xbar,
    const float* __restrict__ Wfold, const float* __restrict__ Wr,
    const float* __restrict__ b0, const float* __restrict__ g0,
    const float* __restrict__ be0, const float* __restrict__ br,
    float* __restrict__ out)
{
    __shared__ float r0[256], r1[256];
    const float SF = 1.0f / sqrtf(1.0f + 1e-5f);
    int g = blockIdx.x, t = threadIdx.x;
    float p0 = 0.0f, p1 = 0.0f;
    for (int c = t; c < 1024; c += 256) {
        float a = acc[g * 1024 + c] + b0[c] * (g0[c] * SF) + be0[c];
        p0 += a * Wr[c * 2];
        p1 += a * Wr[c * 2 + 1];
        float xb = Xbar[g * 1024 + c];
        p0 += xb * Wfold[c * 2];
        p1 += xb * Wfold[c * 2 + 1];
    }
    r0[t] = p0; r1[t] = p1;
    __syncthreads();
    for (int s = 128; s > 0; s >>= 1) {
        if (t < s) { r0[t] += r0[t + s]; r1[t] += r1[t + s]; }
        __syncthreads();
    }
    if (t == 0) {
        out[g * 2 + 0] = r0[0] + br[0];
        out[g * 2 + 1] = r1[0] + br[1];
    }
}

extern "C" void kernel_launch(void* const* d_in, const int* in_sizes, int n_in,
                              void* d_out, int out_size, void* d_ws, size_t ws_size,
                              hipStream_t stream)
{
    const float* x   = (const float*)d_in[0];
    const int*   ei  = (const int*)d_in[1];
    const int* batch = (const int*)d_in[2];
    const float* W0  = (const float*)d_in[3];
    const float* b0  = (const float*)d_in[4];
    const float* g0  = (const float*)d_in[5];
    const float* be0 = (const float*)d_in[6];
    const float* W1  = (const float*)d_in[7];
    const float* b1  = (const float*)d_in[8];
    const float* g1  = (const float*)d_in[9];
    const float* be1 = (const float*)d_in[10];
    const float* W2  = (const float*)d_in[11];
    const float* b2  = (const float*)d_in[12];
    const float* g2  = (const float*)d_in[13];
    const float* be2 = (const float*)d_in[14];
    const float* Wr  = (const float*)d_in[15];
    const float* br  = (const float*)d_in[16];
    float* out = (float*)d_out;

    const int N = in_sizes[2];       // 65536
    const int E = in_sizes[1] / 2;   // 131072

    char* ws = (char*)d_ws;
    size_t off = 0;
    auto alloc = [&](size_t bytes) -> void* {
        off = (off + 255) & ~(size_t)255;
        void* p = ws + off;
        off += bytes;
        return p;
    };
    ushort*   xh     = (ushort*)alloc((size_t)N * 1024 * 2);
    ushort*   Wt     = (ushort*)alloc((size_t)4096 * 1024 * 2);
    float*    biasv  = (float*)alloc(4096 * 4);
    float*    Xbar   = (float*)alloc(64 * 1024 * 4);
    float*    accb   = (float*)alloc(64 * 1024 * 4);
    float*    Wfold  = (float*)alloc(1024 * 2 * 4);
    ushort*   Cbuf   = (ushort*)alloc((size_t)N * 2048 * 2);
    float*    partial= (float*)alloc((size_t)512 * 1024 * 4);
    int*      deg    = (int*)alloc((size_t)N * 4);
    int*      rowptr = (int*)alloc(((size_t)N + 1) * 4);
    int*      cursor = (int*)alloc((size_t)N * 4);
    int*      colb   = (int*)alloc((size_t)E * 4);
    (void)ws_size; (void)n_in; (void)out_size;

    // weight prep + x conversion + block-0 folds
    wbig_kernel<<<dim3(32, 128), 256, 0, stream>>>(W1, W2, g1, g2, Wt);
    bias_kernel<<<16, 256, 0, stream>>>(b1, g1, be1, b2, g2, be2, biasv);
    cvt_kernel<<<(N * 1024 / 8) / 256, 256, 0, stream>>>(x, xh);
    segmean_kernel<<<256, 256, 0, stream>>>(x, batch, Xbar, N);
    wfold_kernel<<<1024, 256, 0, stream>>>(W0, g0, Wr, Wfold);

    // CSR by dst
    zero_kernel<<<(N + 255) / 256, 256, 0, stream>>>(deg, N);
    degcount_kernel<<<(E + 255) / 256, 256, 0, stream>>>(ei, deg, E);
    scan_kernel<<<1, 1024, 0, stream>>>(deg, rowptr, cursor, N, E);
    scatter_kernel<<<(E + 255) / 256, 256, 0, stream>>>(ei, cursor, colb, E);

    for (int blk = 0; blk < 2; ++blk) {
        gemm8_kernel<<<2048, 512, 0, stream>>>(xh, Wt, biasv, Cbuf, blk * 2048);
        edgepool_kernel<<<2048, 256, 0, stream>>>(Cbuf, rowptr, colb, batch, partial, N);
        poolreduce_kernel<<<256, 256, 0, stream>>>(partial, batch, accb, N, blk);
    }
    final_kernel<<<64, 256, 0, stream>>>(accb, Xbar, Wfold, Wr, b0, g0, be0, br, out);
}

// Round 4
// 1309.173 us; speedup vs baseline: 3.8846x; 1.2888x over previous
//
#include <hip/hip_runtime.h>
#include <stdint.h>

#define DD   1024
#define GNUM 64

typedef __attribute__((ext_vector_type(8))) short short8;
typedef __attribute__((ext_vector_type(4))) float f32x4;

__device__ __forceinline__ ushort f2bf(float f) {
    unsigned u = __float_as_uint(f);
    u += 0x7FFFu + ((u >> 16) & 1u);   // RNE
    return (ushort)(u >> 16);
}
__device__ __forceinline__ float bf2f(ushort h) {
    return __uint_as_float(((unsigned)h) << 16);
}

__device__ __forceinline__ void load_lds16(const void* g, void* l) {
    __builtin_amdgcn_global_load_lds(
        (const __attribute__((address_space(1))) unsigned*)(uintptr_t)g,
        (__attribute__((address_space(3))) unsigned*)(uint32_t)(uintptr_t)l,
        16, 0, 0);
}

__device__ __forceinline__ int lbound(const int* a, int n, int v) {
    int lo = 0, hi = n;
    while (lo < hi) { int m = (lo + hi) >> 1; if (a[m] < v) lo = m + 1; else hi = m; }
    return lo;
}

// ---------------------------------------------------------------------------
// Build WbigT [4096][1024] bf16 (transposed weights, BN scale folded in).
// ---------------------------------------------------------------------------
__global__ __launch_bounds__(256) void wbig_kernel(
    const float* __restrict__ W1, const float* __restrict__ W2,
    const float* __restrict__ g1, const float* __restrict__ g2,
    ushort* __restrict__ Wt)
{
    __shared__ float tile[32][33];
    const float SF = 1.0f / sqrtf(1.0f + 1e-5f);
    int k0 = blockIdx.x * 32, c0 = blockIdx.y * 32;
    int tx = threadIdx.x & 31, ty = threadIdx.x >> 5;
    int sec = c0 >> 10;
    int cl = (c0 & 1023) + tx;
    const float* W  = (sec < 2) ? W1 : W2;
    const float* gv = (sec < 2) ? g1 : g2;
    bool isU = (sec & 1) == 0;
    float sc = gv[cl] * SF;
    #pragma unroll
    for (int j = 0; j < 4; ++j) {
        int k = k0 + ty + j * 8;
        float v = isU ? (W[(size_t)k * 1024 + cl] - W[(size_t)(k + 1024) * 1024 + cl]) * sc
                      : W[(size_t)(k + 1024) * 1024 + cl] * sc;
        tile[ty + j * 8][tx] = v;
    }
    __syncthreads();
    #pragma unroll
    for (int j = 0; j < 4; ++j) {
        int cc = ty + j * 8;
        Wt[(size_t)(c0 + cc) * 1024 + k0 + tx] = f2bf(tile[tx][cc]);
    }
}

__global__ __launch_bounds__(256) void bias_kernel(
    const float* __restrict__ b1, const float* __restrict__ g1, const float* __restrict__ be1,
    const float* __restrict__ b2, const float* __restrict__ g2, const float* __restrict__ be2,
    float* __restrict__ biasv)
{
    const float SF = 1.0f / sqrtf(1.0f + 1e-5f);
    int c = blockIdx.x * 256 + threadIdx.x;
    int sec = c >> 10, cl = c & 1023;
    float v = 0.0f;
    if (sec == 0) v = b1[cl] * (g1[cl] * SF) + be1[cl];
    else if (sec == 2) v = b2[cl] * (g2[cl] * SF) + be2[cl];
    biasv[c] = v;
}

// ---------------------------------------------------------------------------
// Fused x->bf16 conversion + per-graph partial sums (for mean pooling of x).
// Block = (graph g, node-subrange sub, d-chunk). Deterministic fixed-order.
// ---------------------------------------------------------------------------
__global__ __launch_bounds__(256) void cvtmean_kernel(
    const float* __restrict__ x, const int* __restrict__ batch,
    ushort* __restrict__ xh, float* __restrict__ partial, int N)
{
    const int b = blockIdx.x;            // 64g * 8sub * 4chunk = 2048
    const int g = b >> 5;
    const int sub = (b >> 2) & 7;
    const int d = ((b & 3) << 8) + threadIdx.x;

    const int glo = lbound(batch, N, g);
    const int ghi = lbound(batch, N, g + 1);
    const int len = ghi - glo;
    const int s0 = glo + (len * sub) / 8;
    const int s1 = glo + (len * (sub + 1)) / 8;

    float sum = 0.0f;
    for (int r = s0; r < s1; ++r) {
        float v = x[(size_t)r * 1024 + d];
        sum += v;
        xh[(size_t)r * 1024 + d] = f2bf(v);
    }
    partial[(size_t)(g * 8 + sub) * 1024 + d] = sum;
}

// Xbar[g][d] = (sum of 8 partials) / count
__global__ __launch_bounds__(256) void xbar_kernel(
    const float* __restrict__ partial, const int* __restrict__ batch,
    float* __restrict__ Xbar, int N)
{
    int g = blockIdx.x >> 2;
    int d = ((blockIdx.x & 3) << 8) + threadIdx.x;
    int glo = lbound(batch, N, g);
    int ghi = lbound(batch, N, g + 1);
    float s = 0.0f;
    #pragma unroll
    for (int k = 0; k < 8; ++k) s += partial[(size_t)(g * 8 + k) * 1024 + d];
    int cnt = ghi - glo; if (cnt < 1) cnt = 1;
    Xbar[g * 1024 + d] = s / (float)cnt;
}

// Wfold[k][o] = sum_c W0[k][c]*s0[c]*Wr[c][o]  -- one block per k, coalesced
__global__ __launch_bounds__(256) void wfold_kernel(
    const float* __restrict__ W0, const float* __restrict__ g0,
    const float* __restrict__ Wr, float* __restrict__ Wfold)
{
    __shared__ float r0s[256], r1s[256];
    const float SF = 1.0f / sqrtf(1.0f + 1e-5f);
    int k = blockIdx.x, t = threadIdx.x;
    float a0 = 0.0f, a1 = 0.0f;
    for (int c = t; c < 1024; c += 256) {
        float w = W0[(size_t)k * 1024 + c] * (g0[c] * SF);
        a0 += w * Wr[c * 2];
        a1 += w * Wr[c * 2 + 1];
    }
    r0s[t] = a0; r1s[t] = a1;
    __syncthreads();
    for (int s = 128; s > 0; s >>= 1) {
        if (t < s) { r0s[t] += r0s[t + s]; r1s[t] += r1s[t + s]; }
        __syncthreads();
    }
    if (t == 0) { Wfold[k * 2] = r0s[0]; Wfold[k * 2 + 1] = r1s[0]; }
}

// ---------------------------------------------------------------------------
// 256x256-tile 8-phase bf16 GEMM (T2 swizzle + T3/T4 counted vmcnt + T5).
// ---------------------------------------------------------------------------
__global__ __launch_bounds__(512, 2) void gemm8_kernel(
    const ushort* __restrict__ A, const ushort* __restrict__ Bt,
    const float* __restrict__ biasv, ushort* __restrict__ C, int nbase)
{
    __shared__ __align__(16) ushort SM[65536];   // 128 KiB
    const int tid  = threadIdx.x;
    const int w    = tid >> 6;
    const int lane = tid & 63;
    const int wr = w >> 2;        // 0..1  (M)
    const int wc = w & 3;         // 0..3  (N)

    const int bx  = blockIdx.x;
    const int swz = (bx & 7) * 256 + (bx >> 3);
    const int m0 = (swz >> 3) * 256;
    const int n0 = (swz & 7) * 256;

    const int srow = lane >> 3;
    const int csw  = ((lane & 7) ^ srow) << 3;

    auto stA = [&](int t, int h) {
        if (t >= 16) return;
        const int c = t & 1;
        const ushort* s = A + (size_t)(m0 + h * 128 + w * 8 + srow) * 1024 + t * 64 + csw;
        ushort* d = SM + c * 16384 + h * 8192 + w * 512;
        load_lds16(s, d);
        load_lds16(s + (size_t)64 * 1024, d + 4096);
    };
    auto stB = [&](int t, int h) {
        if (t >= 16) return;
        const int c = t & 1;
        const ushort* s = Bt + (size_t)(nbase + n0 + h * 128 + w * 8 + srow) * 1024 + t * 64 + csw;
        ushort* d = SM + 32768 + c * 16384 + h * 8192 + w * 512;
        load_lds16(s, d);
        load_lds16(s + (size_t)64 * 1024, d + 4096);
    };

    const int cbk0 = ((lane >> 4) << 4);
    const int cbx  = (lane & 7) << 4;
    auto rdA = [&](int c, int i, int kk) -> short8 {
        int row = i * 16 + (lane & 15);
        int cb  = (kk * 64 + cbk0) ^ cbx;
        return *(const short8*)((const char*)SM + (c * 16384 + wr * 8192) * 2 + row * 128 + cb);
    };
    auto rdB = [&](int c, int j, int kk) -> short8 {
        int row = (wc & 1) * 64 + j * 16 + (lane & 15);
        int cb  = (kk * 64 + cbk0) ^ cbx;
        return *(const short8*)((const char*)SM + 65536 + (c * 16384 + (wc >> 1) * 8192) * 2 + row * 128 + cb);
    };

    f32x4 acc[8][4];
    #pragma unroll
    for (int i = 0; i < 8; ++i)
        #pragma unroll
        for (int j = 0; j < 4; ++j)
            acc[i][j] = (f32x4){0.f, 0.f, 0.f, 0.f};

    short8 afr[4][2], bfr[4][2];

    stA(0, 0); stA(0, 1); stB(0, 0); stB(0, 1); stB(1, 0); stB(1, 1);
    asm volatile("s_waitcnt vmcnt(4)" ::: "memory");
    __builtin_amdgcn_s_barrier();

    for (int t = 0; t < 16; ++t) {
        const int c = t & 1;
        // P1
        #pragma unroll
        for (int i = 0; i < 4; ++i) { afr[i][0] = rdA(c, i, 0); afr[i][1] = rdA(c, i, 1); }
        #pragma unroll
        for (int j = 0; j < 2; ++j) { bfr[j][0] = rdB(c, j, 0); bfr[j][1] = rdB(c, j, 1); }
        stA(t + 1, 0);
        __builtin_amdgcn_s_barrier();
        __builtin_amdgcn_s_setprio(1);
        #pragma unroll
        for (int i = 0; i < 4; ++i)
            #pragma unroll
            for (int j = 0; j < 2; ++j) {
                acc[i][j] = __builtin_amdgcn_mfma_f32_16x16x32_bf16(afr[i][0], bfr[j][0], acc[i][j], 0, 0, 0);
                acc[i][j] = __builtin_amdgcn_mfma_f32_16x16x32_bf16(afr[i][1], bfr[j][1], acc[i][j], 0, 0, 0);
            }
        __builtin_amdgcn_s_setprio(0);
        __builtin_amdgcn_s_barrier();

        // P2
        #pragma unroll
        for (int j = 2; j < 4; ++j) { bfr[j][0] = rdB(c, j, 0); bfr[j][1] = rdB(c, j, 1); }
        stA(t + 1, 1);
        __builtin_amdgcn_s_barrier();
        __builtin_amdgcn_s_setprio(1);
        #pragma unroll
        for (int i = 0; i < 4; ++i)
            #pragma unroll
            for (int j = 2; j < 4; ++j) {
                acc[i][j] = __builtin_amdgcn_mfma_f32_16x16x32_bf16(afr[i][0], bfr[j][0], acc[i][j], 0, 0, 0);
                acc[i][j] = __builtin_amdgcn_mfma_f32_16x16x32_bf16(afr[i][1], bfr[j][1], acc[i][j], 0, 0, 0);
            }
        __builtin_amdgcn_s_setprio(0);
        __builtin_amdgcn_s_barrier();

        // P3
        #pragma unroll
        for (int i = 0; i < 4; ++i) { afr[i][0] = rdA(c, i + 4, 0); afr[i][1] = rdA(c, i + 4, 1); }
        stB(t + 2, 0);
        __builtin_amdgcn_s_barrier();
        __builtin_amdgcn_s_setprio(1);
        #pragma unroll
        for (int i = 0; i < 4; ++i)
            #pragma unroll
            for (int j = 2; j < 4; ++j) {
                acc[i + 4][j] = __builtin_amdgcn_mfma_f32_16x16x32_bf16(afr[i][0], bfr[j][0], acc[i + 4][j], 0, 0, 0);
                acc[i + 4][j] = __builtin_amdgcn_mfma_f32_16x16x32_bf16(afr[i][1], bfr[j][1], acc[i + 4][j], 0, 0, 0);
            }
        __builtin_amdgcn_s_setprio(0);
        __builtin_amdgcn_s_barrier();

        // P4
        stB(t + 2, 1);
        __builtin_amdgcn_s_barrier();
        __builtin_amdgcn_s_setprio(1);
        #pragma unroll
        for (int i = 0; i < 4; ++i)
            #pragma unroll
            for (int j = 0; j < 2; ++j) {
                acc[i + 4][j] = __builtin_amdgcn_mfma_f32_16x16x32_bf16(afr[i][0], bfr[j][0], acc[i + 4][j], 0, 0, 0);
                acc[i + 4][j] = __builtin_amdgcn_mfma_f32_16x16x32_bf16(afr[i][1], bfr[j][1], acc[i + 4][j], 0, 0, 0);
            }
        __builtin_amdgcn_s_setprio(0);
        if (t < 15) {
            if (t < 14) asm volatile("s_waitcnt vmcnt(4)" ::: "memory");
            else        asm volatile("s_waitcnt vmcnt(0)" ::: "memory");
            __builtin_amdgcn_s_barrier();
        }
    }

    const int er = (lane >> 4) << 2;
    const int ec = lane & 15;
    #pragma unroll
    for (int j = 0; j < 4; ++j) {
        int col = n0 + wc * 64 + j * 16 + ec;
        float bv = biasv[nbase + col];
        #pragma unroll
        for (int i = 0; i < 8; ++i) {
            int row = m0 + wr * 128 + i * 16 + er;
            #pragma unroll
            for (int r = 0; r < 4; ++r)
                C[(size_t)(row + r) * 2048 + col] = f2bf(acc[i][j][r] + bv);
        }
    }
}

// ---------------------------------------------------------------------------
// CSR build (shared by both EdgeConv blocks)
// ---------------------------------------------------------------------------
__global__ __launch_bounds__(256) void zero_kernel(int* __restrict__ p, int n) {
    int i = blockIdx.x * 256 + threadIdx.x;
    if (i < n) p[i] = 0;
}

__global__ __launch_bounds__(256) void degcount_kernel(
    const int* __restrict__ ei, int* __restrict__ deg, int E)
{
    int e = blockIdx.x * 256 + threadIdx.x;
    if (e < E) atomicAdd(&deg[ei[E + e]], 1);
}

__global__ __launch_bounds__(1024) void scan_kernel(
    const int* __restrict__ deg, int* __restrict__ rowptr,
    int* __restrict__ cursor, int N, int E)
{
    __shared__ int part[1024];
    int t = threadIdx.x;
    int chunk = N / 1024;
    int base = t * chunk;
    int s = 0;
    for (int i = 0; i < chunk; ++i) s += deg[base + i];
    part[t] = s;
    __syncthreads();
    for (int ofs = 1; ofs < 1024; ofs <<= 1) {
        int v = (t >= ofs) ? part[t - ofs] : 0;
        __syncthreads();
        part[t] += v;
        __syncthreads();
    }
    int run = (t == 0) ? 0 : part[t - 1];
    for (int i = 0; i < chunk; ++i) {
        rowptr[base + i] = run;
        cursor[base + i] = run;
        run += deg[base + i];
    }
    if (t == 1023) rowptr[N] = E;
}

__global__ __launch_bounds__(256) void scatter_kernel(
    const int* __restrict__ ei, int* __restrict__ cursor,
    int* __restrict__ col, int E)
{
    int e = blockIdx.x * 256 + threadIdx.x;
    if (e < E) {
        int d = ei[E + e];
        int pos = atomicAdd(&cursor[d], 1);
        col[pos] = ei[e];
    }
}

// ---------------------------------------------------------------------------
// Fused gather-max + pool partials.
// ---------------------------------------------------------------------------
__global__ __launch_bounds__(256) void edgepool_kernel(
    const ushort* __restrict__ C, const int* __restrict__ rowptr,
    const int* __restrict__ colb, const int* __restrict__ batch,
    float* __restrict__ partial, int N)
{
    const int b = blockIdx.x;            // 64g * 8sub * 4chunk = 2048
    const int g = b >> 5;
    const int sub = (b >> 2) & 7;
    const int d = ((b & 3) << 8) + threadIdx.x;

    const int glo = lbound(batch, N, g);
    const int ghi = lbound(batch, N, g + 1);
    const int len = ghi - glo;
    const int s0 = glo + (len * sub) / 8;
    const int s1 = glo + (len * (sub + 1)) / 8;

    float sum = 0.0f;
    int lo = (s0 < s1) ? rowptr[s0] : 0;
    for (int node = s0; node < s1; ++node) {
        int hi = rowptr[node + 1];
        float vmax = -3.4e38f;
        for (int j = lo; j < hi; ++j) {
            int src = colb[j];
            vmax = fmaxf(vmax, bf2f(C[(size_t)src * 2048 + 1024 + d]));
        }
        float u = bf2f(C[(size_t)node * 2048 + d]);
        sum += (hi > lo) ? (u + vmax) : 0.0f;
        lo = hi;
    }
    partial[(size_t)(g * 8 + sub) * 1024 + d] = sum;
}

// reduce partials -> per-graph mean; mode 0 '=', mode 1 '+='
__global__ __launch_bounds__(256) void poolreduce_kernel(
    const float* __restrict__ partial, const int* __restrict__ batch,
    float* __restrict__ acc, int N, int mode)
{
    int g = blockIdx.x >> 2;
    int d = ((blockIdx.x & 3) << 8) + threadIdx.x;
    int glo = lbound(batch, N, g);
    int ghi = lbound(batch, N, g + 1);
    float s = 0.0f;
    #pragma unroll
    for (int k = 0; k < 8; ++k) s += partial[(size_t)(g * 8 + k) * 1024 + d];
    int cnt = ghi - glo; if (cnt < 1) cnt = 1;
    float v = s / (float)cnt;
    float* p = acc + g * 1024 + d;
    if (mode) *p += v; else *p = v;
}

__global__ __launch_bounds__(256) void final_kernel(
    const float* __restrict__ acc, const float* __restrict__ Xbar,
    const float* __restrict__ Wfold, const float* __restrict__ Wr,
    const float* __restrict__ b0, const float* __restrict__ g0,
    const float* __restrict__ be0, const float* __restrict__ br,
    float* __restrict__ out)
{
    __shared__ float r0[256], r1[256];
    const float SF = 1.0f / sqrtf(1.0f + 1e-5f);
    int g = blockIdx.x, t = threadIdx.x;
    float p0 = 0.0f, p1 = 0.0f;
    for (int c = t; c < 1024; c += 256) {
        float a = acc[g * 1024 + c] + b0[c] * (g0[c] * SF) + be0[c];
        p0 += a * Wr[c * 2];
        p1 += a * Wr[c * 2 + 1];
        float xb = Xbar[g * 1024 + c];
        p0 += xb * Wfold[c * 2];
        p1 += xb * Wfold[c * 2 + 1];
    }
    r0[t] = p0; r1[t] = p1;
    __syncthreads();
    for (int s = 128; s > 0; s >>= 1) {
        if (t < s) { r0[t] += r0[t + s]; r1[t] += r1[t + s]; }
        __syncthreads();
    }
    if (t == 0) {
        out[g * 2 + 0] = r0[0] + br[0];
        out[g * 2 + 1] = r1[0] + br[1];
    }
}

extern "C" void kernel_launch(void* const* d_in, const int* in_sizes, int n_in,
                              void* d_out, int out_size, void* d_ws, size_t ws_size,
                              hipStream_t stream)
{
    const float* x   = (const float*)d_in[0];
    const int*   ei  = (const int*)d_in[1];
    const int* batch = (const int*)d_in[2];
    const float* W0  = (const float*)d_in[3];
    const float* b0  = (const float*)d_in[4];
    const float* g0  = (const float*)d_in[5];
    const float* be0 = (const float*)d_in[6];
    const float* W1  = (const float*)d_in[7];
    const float* b1  = (const float*)d_in[8];
    const float* g1  = (const float*)d_in[9];
    const float* be1 = (const float*)d_in[10];
    const float* W2  = (const float*)d_in[11];
    const float* b2  = (const float*)d_in[12];
    const float* g2  = (const float*)d_in[13];
    const float* be2 = (const float*)d_in[14];
    const float* Wr  = (const float*)d_in[15];
    const float* br  = (const float*)d_in[16];
    float* out = (float*)d_out;

    const int N = in_sizes[2];       // 65536
    const int E = in_sizes[1] / 2;   // 131072

    char* ws = (char*)d_ws;
    size_t off = 0;
    auto alloc = [&](size_t bytes) -> void* {
        off = (off + 255) & ~(size_t)255;
        void* p = ws + off;
        off += bytes;
        return p;
    };
    ushort*   xh      = (ushort*)alloc((size_t)N * 1024 * 2);
    ushort*   Wt      = (ushort*)alloc((size_t)4096 * 1024 * 2);
    float*    biasv   = (float*)alloc(4096 * 4);
    float*    Xbar    = (float*)alloc(64 * 1024 * 4);
    float*    accb    = (float*)alloc(64 * 1024 * 4);
    float*    Wfold   = (float*)alloc(1024 * 2 * 4);
    ushort*   Cbuf    = (ushort*)alloc((size_t)N * 2048 * 2);
    float*    partial = (float*)alloc((size_t)512 * 1024 * 4);
    float*    partmean= (float*)alloc((size_t)512 * 1024 * 4);
    int*      deg     = (int*)alloc((size_t)N * 4);
    int*      rowptr  = (int*)alloc(((size_t)N + 1) * 4);
    int*      cursor  = (int*)alloc((size_t)N * 4);
    int*      colb    = (int*)alloc((size_t)E * 4);
    (void)ws_size; (void)n_in; (void)out_size;

    // fused x conversion + mean partials; weight prep; block-0 folds
    cvtmean_kernel<<<2048, 256, 0, stream>>>(x, batch, xh, partmean, N);
    xbar_kernel<<<256, 256, 0, stream>>>(partmean, batch, Xbar, N);
    wbig_kernel<<<dim3(32, 128), 256, 0, stream>>>(W1, W2, g1, g2, Wt);
    bias_kernel<<<16, 256, 0, stream>>>(b1, g1, be1, b2, g2, be2, biasv);
    wfold_kernel<<<1024, 256, 0, stream>>>(W0, g0, Wr, Wfold);

    // CSR by dst
    zero_kernel<<<(N + 255) / 256, 256, 0, stream>>>(deg, N);
    degcount_kernel<<<(E + 255) / 256, 256, 0, stream>>>(ei, deg, E);
    scan_kernel<<<1, 1024, 0, stream>>>(deg, rowptr, cursor, N, E);
    scatter_kernel<<<(E + 255) / 256, 256, 0, stream>>>(ei, cursor, colb, E);

    for (int blk = 0; blk < 2; ++blk) {
        gemm8_kernel<<<2048, 512, 0, stream>>>(xh, Wt, biasv, Cbuf, blk * 2048);
        edgepool_kernel<<<2048, 256, 0, stream>>>(Cbuf, rowptr, colb, batch, partial, N);
        poolreduce_kernel<<<256, 256, 0, stream>>>(partial, batch, accb, N, blk);
    }
    final_kernel<<<64, 256, 0, stream>>>(accb, Xbar, Wfold, Wr, b0, g0, be0, br, out);
}

// Round 5
// 1251.880 us; speedup vs baseline: 4.0624x; 1.0458x over previous
//
#include <hip/hip_runtime.h>
#include <stdint.h>

#define DD   1024
#define GNUM 64

typedef __attribute__((ext_vector_type(8))) short short8;
typedef __attribute__((ext_vector_type(4))) float f32x4;

__device__ __forceinline__ ushort f2bf(float f) {
    unsigned u = __float_as_uint(f);
    u += 0x7FFFu + ((u >> 16) & 1u);   // RNE
    return (ushort)(u >> 16);
}
__device__ __forceinline__ float bf2f(ushort h) {
    return __uint_as_float(((unsigned)h) << 16);
}

__device__ __forceinline__ void load_lds16(const void* g, void* l) {
    __builtin_amdgcn_global_load_lds(
        (const __attribute__((address_space(1))) unsigned*)(uintptr_t)g,
        (__attribute__((address_space(3))) unsigned*)(uint32_t)(uintptr_t)l,
        16, 0, 0);
}

__device__ __forceinline__ int lbound(const int* a, int n, int v) {
    int lo = 0, hi = n;
    while (lo < hi) { int m = (lo + hi) >> 1; if (a[m] < v) lo = m + 1; else hi = m; }
    return lo;
}

// ---------------------------------------------------------------------------
// Build WbigT [4096][1024] bf16 (transposed weights, BN scale folded in).
// ---------------------------------------------------------------------------
__global__ __launch_bounds__(256) void wbig_kernel(
    const float* __restrict__ W1, const float* __restrict__ W2,
    const float* __restrict__ g1, const float* __restrict__ g2,
    ushort* __restrict__ Wt)
{
    __shared__ float tile[32][33];
    const float SF = 1.0f / sqrtf(1.0f + 1e-5f);
    int k0 = blockIdx.x * 32, c0 = blockIdx.y * 32;
    int tx = threadIdx.x & 31, ty = threadIdx.x >> 5;
    int sec = c0 >> 10;
    int cl = (c0 & 1023) + tx;
    const float* W  = (sec < 2) ? W1 : W2;
    const float* gv = (sec < 2) ? g1 : g2;
    bool isU = (sec & 1) == 0;
    float sc = gv[cl] * SF;
    #pragma unroll
    for (int j = 0; j < 4; ++j) {
        int k = k0 + ty + j * 8;
        float v = isU ? (W[(size_t)k * 1024 + cl] - W[(size_t)(k + 1024) * 1024 + cl]) * sc
                      : W[(size_t)(k + 1024) * 1024 + cl] * sc;
        tile[ty + j * 8][tx] = v;
    }
    __syncthreads();
    #pragma unroll
    for (int j = 0; j < 4; ++j) {
        int cc = ty + j * 8;
        Wt[(size_t)(c0 + cc) * 1024 + k0 + tx] = f2bf(tile[tx][cc]);
    }
}

__global__ __launch_bounds__(256) void bias_kernel(
    const float* __restrict__ b1, const float* __restrict__ g1, const float* __restrict__ be1,
    const float* __restrict__ b2, const float* __restrict__ g2, const float* __restrict__ be2,
    float* __restrict__ biasv)
{
    const float SF = 1.0f / sqrtf(1.0f + 1e-5f);
    int c = blockIdx.x * 256 + threadIdx.x;
    int sec = c >> 10, cl = c & 1023;
    float v = 0.0f;
    if (sec == 0) v = b1[cl] * (g1[cl] * SF) + be1[cl];
    else if (sec == 2) v = b2[cl] * (g2[cl] * SF) + be2[cl];
    biasv[c] = v;
}

// ---------------------------------------------------------------------------
// Fused x->bf16 conversion + per-graph partial sums (for mean pooling of x).
// ---------------------------------------------------------------------------
__global__ __launch_bounds__(256) void cvtmean_kernel(
    const float* __restrict__ x, const int* __restrict__ batch,
    ushort* __restrict__ xh, float* __restrict__ partial, int N)
{
    const int b = blockIdx.x;            // 64g * 8sub * 4chunk = 2048
    const int g = b >> 5;
    const int sub = (b >> 2) & 7;
    const int d = ((b & 3) << 8) + threadIdx.x;

    const int glo = lbound(batch, N, g);
    const int ghi = lbound(batch, N, g + 1);
    const int len = ghi - glo;
    const int s0 = glo + (len * sub) / 8;
    const int s1 = glo + (len * (sub + 1)) / 8;

    float sum = 0.0f;
    for (int r = s0; r < s1; ++r) {
        float v = x[(size_t)r * 1024 + d];
        sum += v;
        xh[(size_t)r * 1024 + d] = f2bf(v);
    }
    partial[(size_t)(g * 8 + sub) * 1024 + d] = sum;
}

// Xbar[g][d] = (sum of 8 partials) / count
__global__ __launch_bounds__(256) void xbar_kernel(
    const float* __restrict__ partial, const int* __restrict__ batch,
    float* __restrict__ Xbar, int N)
{
    int g = blockIdx.x >> 2;
    int d = ((blockIdx.x & 3) << 8) + threadIdx.x;
    int glo = lbound(batch, N, g);
    int ghi = lbound(batch, N, g + 1);
    float s = 0.0f;
    #pragma unroll
    for (int k = 0; k < 8; ++k) s += partial[(size_t)(g * 8 + k) * 1024 + d];
    int cnt = ghi - glo; if (cnt < 1) cnt = 1;
    Xbar[g * 1024 + d] = s / (float)cnt;
}

// Wfold[k][o] = sum_c W0[k][c]*s0[c]*Wr[c][o]
__global__ __launch_bounds__(256) void wfold_kernel(
    const float* __restrict__ W0, const float* __restrict__ g0,
    const float* __restrict__ Wr, float* __restrict__ Wfold)
{
    __shared__ float r0s[256], r1s[256];
    const float SF = 1.0f / sqrtf(1.0f + 1e-5f);
    int k = blockIdx.x, t = threadIdx.x;
    float a0 = 0.0f, a1 = 0.0f;
    for (int c = t; c < 1024; c += 256) {
        float w = W0[(size_t)k * 1024 + c] * (g0[c] * SF);
        a0 += w * Wr[c * 2];
        a1 += w * Wr[c * 2 + 1];
    }
    r0s[t] = a0; r1s[t] = a1;
    __syncthreads();
    for (int s = 128; s > 0; s >>= 1) {
        if (t < s) { r0s[t] += r0s[t + s]; r1s[t] += r1s[t + s]; }
        __syncthreads();
    }
    if (t == 0) { Wfold[k * 2] = r0s[0]; Wfold[k * 2 + 1] = r1s[0]; }
}

// ---------------------------------------------------------------------------
// 256x256-tile 8-phase bf16 GEMM (T2 swizzle + T3/T4 counted vmcnt + T5).
// MFMA operands SWAPPED (D = C^T fragment): lane owns 1 row x 4 consecutive
// cols -> 8B packed LDS epilogue + coalesced dwordx4 global stores.
// ---------------------------------------------------------------------------
__global__ __launch_bounds__(512, 2) void gemm8_kernel(
    const ushort* __restrict__ A, const ushort* __restrict__ Bt,
    const float* __restrict__ biasv, ushort* __restrict__ C, int nbase)
{
    __shared__ __align__(16) ushort SM[65536];   // 128 KiB
    const int tid  = threadIdx.x;
    const int w    = tid >> 6;
    const int lane = tid & 63;
    const int wr = w >> 2;        // 0..1  (M)
    const int wc = w & 3;         // 0..3  (N)

    const int bx  = blockIdx.x;
    const int swz = (bx & 7) * 256 + (bx >> 3);
    const int m0 = (swz >> 3) * 256;
    const int n0 = (swz & 7) * 256;

    const int srow = lane >> 3;
    const int csw  = ((lane & 7) ^ srow) << 3;

    auto stA = [&](int t, int h) {
        if (t >= 16) return;
        const int c = t & 1;
        const ushort* s = A + (size_t)(m0 + h * 128 + w * 8 + srow) * 1024 + t * 64 + csw;
        ushort* d = SM + c * 16384 + h * 8192 + w * 512;
        load_lds16(s, d);
        load_lds16(s + (size_t)64 * 1024, d + 4096);
    };
    auto stB = [&](int t, int h) {
        if (t >= 16) return;
        const int c = t & 1;
        const ushort* s = Bt + (size_t)(nbase + n0 + h * 128 + w * 8 + srow) * 1024 + t * 64 + csw;
        ushort* d = SM + 32768 + c * 16384 + h * 8192 + w * 512;
        load_lds16(s, d);
        load_lds16(s + (size_t)64 * 1024, d + 4096);
    };

    const int cbk0 = ((lane >> 4) << 4);
    const int cbx  = (lane & 7) << 4;
    auto rdA = [&](int c, int i, int kk) -> short8 {
        int row = i * 16 + (lane & 15);
        int cb  = (kk * 64 + cbk0) ^ cbx;
        return *(const short8*)((const char*)SM + (c * 16384 + wr * 8192) * 2 + row * 128 + cb);
    };
    auto rdB = [&](int c, int j, int kk) -> short8 {
        int row = (wc & 1) * 64 + j * 16 + (lane & 15);
        int cb  = (kk * 64 + cbk0) ^ cbx;
        return *(const short8*)((const char*)SM + 65536 + (c * 16384 + (wc >> 1) * 8192) * 2 + row * 128 + cb);
    };

    f32x4 acc[8][4];
    #pragma unroll
    for (int i = 0; i < 8; ++i)
        #pragma unroll
        for (int j = 0; j < 4; ++j)
            acc[i][j] = (f32x4){0.f, 0.f, 0.f, 0.f};

    short8 afr[4][2], bfr[4][2];

    stA(0, 0); stA(0, 1); stB(0, 0); stB(0, 1); stB(1, 0); stB(1, 1);
    asm volatile("s_waitcnt vmcnt(4)" ::: "memory");
    __builtin_amdgcn_s_barrier();

    for (int t = 0; t < 16; ++t) {
        const int c = t & 1;
        // P1
        #pragma unroll
        for (int i = 0; i < 4; ++i) { afr[i][0] = rdA(c, i, 0); afr[i][1] = rdA(c, i, 1); }
        #pragma unroll
        for (int j = 0; j < 2; ++j) { bfr[j][0] = rdB(c, j, 0); bfr[j][1] = rdB(c, j, 1); }
        stA(t + 1, 0);
        __builtin_amdgcn_s_barrier();
        __builtin_amdgcn_s_setprio(1);
        #pragma unroll
        for (int i = 0; i < 4; ++i)
            #pragma unroll
            for (int j = 0; j < 2; ++j) {
                acc[i][j] = __builtin_amdgcn_mfma_f32_16x16x32_bf16(bfr[j][0], afr[i][0], acc[i][j], 0, 0, 0);
                acc[i][j] = __builtin_amdgcn_mfma_f32_16x16x32_bf16(bfr[j][1], afr[i][1], acc[i][j], 0, 0, 0);
            }
        __builtin_amdgcn_s_setprio(0);
        __builtin_amdgcn_s_barrier();

        // P2
        #pragma unroll
        for (int j = 2; j < 4; ++j) { bfr[j][0] = rdB(c, j, 0); bfr[j][1] = rdB(c, j, 1); }
        stA(t + 1, 1);
        __builtin_amdgcn_s_barrier();
        __builtin_amdgcn_s_setprio(1);
        #pragma unroll
        for (int i = 0; i < 4; ++i)
            #pragma unroll
            for (int j = 2; j < 4; ++j) {
                acc[i][j] = __builtin_amdgcn_mfma_f32_16x16x32_bf16(bfr[j][0], afr[i][0], acc[i][j], 0, 0, 0);
                acc[i][j] = __builtin_amdgcn_mfma_f32_16x16x32_bf16(bfr[j][1], afr[i][1], acc[i][j], 0, 0, 0);
            }
        __builtin_amdgcn_s_setprio(0);
        __builtin_amdgcn_s_barrier();

        // P3
        #pragma unroll
        for (int i = 0; i < 4; ++i) { afr[i][0] = rdA(c, i + 4, 0); afr[i][1] = rdA(c, i + 4, 1); }
        stB(t + 2, 0);
        __builtin_amdgcn_s_barrier();
        __builtin_amdgcn_s_setprio(1);
        #pragma unroll
        for (int i = 0; i < 4; ++i)
            #pragma unroll
            for (int j = 2; j < 4; ++j) {
                acc[i + 4][j] = __builtin_amdgcn_mfma_f32_16x16x32_bf16(bfr[j][0], afr[i][0], acc[i + 4][j], 0, 0, 0);
                acc[i + 4][j] = __builtin_amdgcn_mfma_f32_16x16x32_bf16(bfr[j][1], afr[i][1], acc[i + 4][j], 0, 0, 0);
            }
        __builtin_amdgcn_s_setprio(0);
        __builtin_amdgcn_s_barrier();

        // P4
        stB(t + 2, 1);
        __builtin_amdgcn_s_barrier();
        __builtin_amdgcn_s_setprio(1);
        #pragma unroll
        for (int i = 0; i < 4; ++i)
            #pragma unroll
            for (int j = 0; j < 2; ++j) {
                acc[i + 4][j] = __builtin_amdgcn_mfma_f32_16x16x32_bf16(bfr[j][0], afr[i][0], acc[i + 4][j], 0, 0, 0);
                acc[i + 4][j] = __builtin_amdgcn_mfma_f32_16x16x32_bf16(bfr[j][1], afr[i][1], acc[i + 4][j], 0, 0, 0);
            }
        __builtin_amdgcn_s_setprio(0);
        if (t < 15) {
            if (t < 14) asm volatile("s_waitcnt vmcnt(4)" ::: "memory");
            else        asm volatile("s_waitcnt vmcnt(0)" ::: "memory");
            __builtin_amdgcn_s_barrier();
        }
    }

    // ---- epilogue: LDS transpose-stage, then coalesced stores ----
    // lane holds (swapped D): row m = wr*128 + i*16 + (lane&15),
    // cols n = wc*64 + j*16 + (lane>>4)*4 + {0..3}  (4 consecutive)
    __syncthreads();   // all waves done reading K-loop LDS
    {
        const int mls = wr * 128 + (lane & 15);
        const int nls = wc * 64 + ((lane >> 4) << 2);
        #pragma unroll
        for (int j = 0; j < 4; ++j) {
            const int nl = nls + j * 16;
            const float4 bv = *(const float4*)&biasv[nbase + n0 + nl];
            #pragma unroll
            for (int i = 0; i < 8; ++i) {
                const int ml = mls + i * 16;
                unsigned lo = (unsigned)f2bf(acc[i][j][0] + bv.x) |
                              ((unsigned)f2bf(acc[i][j][1] + bv.y) << 16);
                unsigned hi = (unsigned)f2bf(acc[i][j][2] + bv.z) |
                              ((unsigned)f2bf(acc[i][j][3] + bv.w) << 16);
                int u = (ml * 256 + nl) ^ (((ml >> 2) & 3) << 4);
                *(uint2*)(SM + u) = make_uint2(lo, hi);
            }
        }
    }
    __syncthreads();
    #pragma unroll
    for (int p = 0; p < 16; ++p) {
        const int row = p * 16 + (tid >> 5);
        const int cu  = (tid & 31) * 8;
        int u = (row * 256 + cu) ^ (((row >> 2) & 3) << 4);
        short8 v = *(const short8*)(SM + u);
        *(short8*)(&C[(size_t)(m0 + row) * 2048 + n0 + cu]) = v;
    }
}

// ---------------------------------------------------------------------------
// CSR build (shared by both EdgeConv blocks)
// ---------------------------------------------------------------------------
__global__ __launch_bounds__(256) void zero_kernel(int* __restrict__ p, int n) {
    int i = blockIdx.x * 256 + threadIdx.x;
    if (i < n) p[i] = 0;
}

__global__ __launch_bounds__(256) void degcount_kernel(
    const int* __restrict__ ei, int* __restrict__ deg, int E)
{
    int e = blockIdx.x * 256 + threadIdx.x;
    if (e < E) atomicAdd(&deg[ei[E + e]], 1);
}

__global__ __launch_bounds__(1024) void scan_kernel(
    const int* __restrict__ deg, int* __restrict__ rowptr,
    int* __restrict__ cursor, int N, int E)
{
    __shared__ int part[1024];
    int t = threadIdx.x;
    int chunk = N / 1024;
    int base = t * chunk;
    int s = 0;
    for (int i = 0; i < chunk; ++i) s += deg[base + i];
    part[t] = s;
    __syncthreads();
    for (int ofs = 1; ofs < 1024; ofs <<= 1) {
        int v = (t >= ofs) ? part[t - ofs] : 0;
        __syncthreads();
        part[t] += v;
        __syncthreads();
    }
    int run = (t == 0) ? 0 : part[t - 1];
    for (int i = 0; i < chunk; ++i) {
        rowptr[base + i] = run;
        cursor[base + i] = run;
        run += deg[base + i];
    }
    if (t == 1023) rowptr[N] = E;
}

__global__ __launch_bounds__(256) void scatter_kernel(
    const int* __restrict__ ei, int* __restrict__ cursor,
    int* __restrict__ col, int E)
{
    int e = blockIdx.x * 256 + threadIdx.x;
    if (e < E) {
        int d = ei[E + e];
        int pos = atomicAdd(&cursor[d], 1);
        col[pos] = ei[e];
    }
}

// ---------------------------------------------------------------------------
// Fused gather-max + pool partials.
// ---------------------------------------------------------------------------
__global__ __launch_bounds__(256) void edgepool_kernel(
    const ushort* __restrict__ C, const int* __restrict__ rowptr,
    const int* __restrict__ colb, const int* __restrict__ batch,
    float* __restrict__ partial, int N)
{
    const int b = blockIdx.x;            // 64g * 8sub * 4chunk = 2048
    const int g = b >> 5;
    const int sub = (b >> 2) & 7;
    const int d = ((b & 3) << 8) + threadIdx.x;

    const int glo = lbound(batch, N, g);
    const int ghi = lbound(batch, N, g + 1);
    const int len = ghi - glo;
    const int s0 = glo + (len * sub) / 8;
    const int s1 = glo + (len * (sub + 1)) / 8;

    float sum = 0.0f;
    int lo = (s0 < s1) ? rowptr[s0] : 0;
    for (int node = s0; node < s1; ++node) {
        int hi = rowptr[node + 1];
        float vmax = -3.4e38f;
        for (int j = lo; j < hi; ++j) {
            int src = colb[j];
            vmax = fmaxf(vmax, bf2f(C[(size_t)src * 2048 + 1024 + d]));
        }
        float u = bf2f(C[(size_t)node * 2048 + d]);
        sum += (hi > lo) ? (u + vmax) : 0.0f;
        lo = hi;
    }
    partial[(size_t)(g * 8 + sub) * 1024 + d] = sum;
}

// reduce partials -> per-graph mean; mode 0 '=', mode 1 '+='
__global__ __launch_bounds__(256) void poolreduce_kernel(
    const float* __restrict__ partial, const int* __restrict__ batch,
    float* __restrict__ acc, int N, int mode)
{
    int g = blockIdx.x >> 2;
    int d = ((blockIdx.x & 3) << 8) + threadIdx.x;
    int glo = lbound(batch, N, g);
    int ghi = lbound(batch, N, g + 1);
    float s = 0.0f;
    #pragma unroll
    for (int k = 0; k < 8; ++k) s += partial[(size_t)(g * 8 + k) * 1024 + d];
    int cnt = ghi - glo; if (cnt < 1) cnt = 1;
    float v = s / (float)cnt;
    float* p = acc + g * 1024 + d;
    if (mode) *p += v; else *p = v;
}

__global__ __launch_bounds__(256) void final_kernel(
    const float* __restrict__ acc, const float* __restrict__ Xbar,
    const float* __restrict__ Wfold, const float* __restrict__ Wr,
    const float* __restrict__ b0, const float* __restrict__ g0,
    const float* __restrict__ be0, const float* __restrict__ br,
    float* __restrict__ out)
{
    __shared__ float r0[256], r1[256];
    const float SF = 1.0f / sqrtf(1.0f + 1e-5f);
    int g = blockIdx.x, t = threadIdx.x;
    float p0 = 0.0f, p1 = 0.0f;
    for (int c = t; c < 1024; c += 256) {
        float a = acc[g * 1024 + c] + b0[c] * (g0[c] * SF) + be0[c];
        p0 += a * Wr[c * 2];
        p1 += a * Wr[c * 2 + 1];
        float xb = Xbar[g * 1024 + c];
        p0 += xb * Wfold[c * 2];
        p1 += xb * Wfold[c * 2 + 1];
    }
    r0[t] = p0; r1[t] = p1;
    __syncthreads();
    for (int s = 128; s > 0; s >>= 1) {
        if (t < s) { r0[t] += r0[t + s]; r1[t] += r1[t + s]; }
        __syncthreads();
    }
    if (t == 0) {
        out[g * 2 + 0] = r0[0] + br[0];
        out[g * 2 + 1] = r1[0] + br[1];
    }
}

extern "C" void kernel_launch(void* const* d_in, const int* in_sizes, int n_in,
                              void* d_out, int out_size, void* d_ws, size_t ws_size,
                              hipStream_t stream)
{
    const float* x   = (const float*)d_in[0];
    const int*   ei  = (const int*)d_in[1];
    const int* batch = (const int*)d_in[2];
    const float* W0  = (const float*)d_in[3];
    const float* b0  = (const float*)d_in[4];
    const float* g0  = (const float*)d_in[5];
    const float* be0 = (const float*)d_in[6];
    const float* W1  = (const float*)d_in[7];
    const float* b1  = (const float*)d_in[8];
    const float* g1  = (const float*)d_in[9];
    const float* be1 = (const float*)d_in[10];
    const float* W2  = (const float*)d_in[11];
    const float* b2  = (const float*)d_in[12];
    const float* g2  = (const float*)d_in[13];
    const float* be2 = (const float*)d_in[14];
    const float* Wr  = (const float*)d_in[15];
    const float* br  = (const float*)d_in[16];
    float* out = (float*)d_out;

    const int N = in_sizes[2];       // 65536
    const int E = in_sizes[1] / 2;   // 131072

    char* ws = (char*)d_ws;
    size_t off = 0;
    auto alloc = [&](size_t bytes) -> void* {
        off = (off + 255) & ~(size_t)255;
        void* p = ws + off;
        off += bytes;
        return p;
    };
    ushort*   xh      = (ushort*)alloc((size_t)N * 1024 * 2);
    ushort*   Wt      = (ushort*)alloc((size_t)4096 * 1024 * 2);
    float*    biasv   = (float*)alloc(4096 * 4);
    float*    Xbar    = (float*)alloc(64 * 1024 * 4);
    float*    accb    = (float*)alloc(64 * 1024 * 4);
    float*    Wfold   = (float*)alloc(1024 * 2 * 4);
    ushort*   Cbuf    = (ushort*)alloc((size_t)N * 2048 * 2);
    float*    partial = (float*)alloc((size_t)512 * 1024 * 4);
    float*    partmean= (float*)alloc((size_t)512 * 1024 * 4);
    int*      deg     = (int*)alloc((size_t)N * 4);
    int*      rowptr  = (int*)alloc(((size_t)N + 1) * 4);
    int*      cursor  = (int*)alloc((size_t)N * 4);
    int*      colb    = (int*)alloc((size_t)E * 4);
    (void)ws_size; (void)n_in; (void)out_size;

    cvtmean_kernel<<<2048, 256, 0, stream>>>(x, batch, xh, partmean, N);
    xbar_kernel<<<256, 256, 0, stream>>>(partmean, batch, Xbar, N);
    wbig_kernel<<<dim3(32, 128), 256, 0, stream>>>(W1, W2, g1, g2, Wt);
    bias_kernel<<<16, 256, 0, stream>>>(b1, g1, be1, b2, g2, be2, biasv);
    wfold_kernel<<<1024, 256, 0, stream>>>(W0, g0, Wr, Wfold);

    zero_kernel<<<(N + 255) / 256, 256, 0, stream>>>(deg, N);
    degcount_kernel<<<(E + 255) / 256, 256, 0, stream>>>(ei, deg, E);
    scan_kernel<<<1, 1024, 0, stream>>>(deg, rowptr, cursor, N, E);
    scatter_kernel<<<(E + 255) / 256, 256, 0, stream>>>(ei, cursor, colb, E);

    for (int blk = 0; blk < 2; ++blk) {
        gemm8_kernel<<<2048, 512, 0, stream>>>(xh, Wt, biasv, Cbuf, blk * 2048);
        edgepool_kernel<<<2048, 256, 0, stream>>>(Cbuf, rowptr, colb, batch, partial, N);
        poolreduce_kernel<<<256, 256, 0, stream>>>(partial, batch, accb, N, blk);
    }
    final_kernel<<<64, 256, 0, stream>>>(accb, Xbar, Wfold, Wr, b0, g0, be0, br, out);
}

// Round 6
// 667.165 us; speedup vs baseline: 7.6227x; 1.8764x over previous
//
#include <hip/hip_runtime.h>
#include <stdint.h>

#define DD   1024
#define GNUM 64

typedef __attribute__((ext_vector_type(8))) short short8;
typedef __attribute__((ext_vector_type(4))) float f32x4;

__device__ __forceinline__ ushort f2bf(float f) {
    unsigned u = __float_as_uint(f);
    u += 0x7FFFu + ((u >> 16) & 1u);   // RNE
    return (ushort)(u >> 16);
}
__device__ __forceinline__ float bf2f(ushort h) {
    return __uint_as_float(((unsigned)h) << 16);
}

__device__ __forceinline__ void load_lds16(const void* g, void* l) {
    __builtin_amdgcn_global_load_lds(
        (const __attribute__((address_space(1))) unsigned*)(uintptr_t)g,
        (__attribute__((address_space(3))) unsigned*)(uint32_t)(uintptr_t)l,
        16, 0, 0);
}

__device__ __forceinline__ int lbound(const int* a, int n, int v) {
    int lo = 0, hi = n;
    while (lo < hi) { int m = (lo + hi) >> 1; if (a[m] < v) lo = m + 1; else hi = m; }
    return lo;
}

// ---------------------------------------------------------------------------
// CSR build (by dst). Counts deterministic; intra-bucket order irrelevant
// (fp max is order-invariant).
// ---------------------------------------------------------------------------
__global__ __launch_bounds__(256) void zero_kernel(int* __restrict__ p, int n) {
    int i = blockIdx.x * 256 + threadIdx.x;
    if (i < n) p[i] = 0;
}

__global__ __launch_bounds__(256) void degcount_kernel(
    const int* __restrict__ ei, int* __restrict__ deg, int E)
{
    int e = blockIdx.x * 256 + threadIdx.x;
    if (e < E) atomicAdd(&deg[ei[E + e]], 1);
}

__global__ __launch_bounds__(1024) void scan_kernel(
    const int* __restrict__ deg, int* __restrict__ rowptr,
    int* __restrict__ cursor, int N, int E)
{
    __shared__ int part[1024];
    int t = threadIdx.x;
    int chunk = N / 1024;
    int base = t * chunk;
    int s = 0;
    for (int i = 0; i < chunk; ++i) s += deg[base + i];
    part[t] = s;
    __syncthreads();
    for (int ofs = 1; ofs < 1024; ofs <<= 1) {
        int v = (t >= ofs) ? part[t - ofs] : 0;
        __syncthreads();
        part[t] += v;
        __syncthreads();
    }
    int run = (t == 0) ? 0 : part[t - 1];
    for (int i = 0; i < chunk; ++i) {
        rowptr[base + i] = run;
        cursor[base + i] = run;
        run += deg[base + i];
    }
    if (t == 1023) rowptr[N] = E;
}

__global__ __launch_bounds__(256) void scatter_kernel(
    const int* __restrict__ ei, int* __restrict__ cursor,
    int* __restrict__ col, int E)
{
    int e = blockIdx.x * 256 + threadIdx.x;
    if (e < E) {
        int d = ei[E + e];
        int pos = atomicAdd(&cursor[d], 1);
        col[pos] = ei[e];
    }
}

// ---------------------------------------------------------------------------
// Fused x->bf16 + per-graph partial sums (all nodes, and deg>0 nodes only).
// Block = (g, sub) of 64x32; thread owns 4 cols (float4 loads).
// ---------------------------------------------------------------------------
__global__ __launch_bounds__(256) void cvtmean_kernel(
    const float* __restrict__ x, const int* __restrict__ batch,
    const int* __restrict__ deg, ushort* __restrict__ xh,
    float* __restrict__ pm, float* __restrict__ pp, int N)
{
    const int b = blockIdx.x;          // 64*32
    const int g = b >> 5, sub = b & 31;
    const int d4 = threadIdx.x * 4;

    const int glo = lbound(batch, N, g);
    const int ghi = lbound(batch, N, g + 1);
    const int len = ghi - glo;
    const int s0 = glo + (len * sub) / 32;
    const int s1 = glo + (len * (sub + 1)) / 32;

    float4 sum = make_float4(0.f, 0.f, 0.f, 0.f);
    float4 sump = make_float4(0.f, 0.f, 0.f, 0.f);
    for (int r = s0; r < s1; ++r) {
        float4 v = *(const float4*)(x + (size_t)r * 1024 + d4);
        sum.x += v.x; sum.y += v.y; sum.z += v.z; sum.w += v.w;
        if (deg[r] > 0) { sump.x += v.x; sump.y += v.y; sump.z += v.z; sump.w += v.w; }
        ushort4 h = make_ushort4(f2bf(v.x), f2bf(v.y), f2bf(v.z), f2bf(v.w));
        *(ushort4*)(xh + (size_t)r * 1024 + d4) = h;
    }
    size_t o = (size_t)(g * 32 + sub) * 1024 + d4;
    *(float4*)(pm + o) = sum;
    *(float4*)(pp + o) = sump;
}

// Xbar[g][c] = sum(pm)/cnt ; xsum_pos[g][c] = sum(pp) (raw)
__global__ __launch_bounds__(256) void xbar2_kernel(
    const float* __restrict__ pm, const float* __restrict__ pp,
    const int* __restrict__ batch, float* __restrict__ Xbar,
    float* __restrict__ xsp, int N)
{
    int g = blockIdx.x >> 2;
    int c = ((blockIdx.x & 3) << 8) + threadIdx.x;
    float s = 0.f, sp = 0.f;
    #pragma unroll
    for (int k = 0; k < 32; ++k) {
        s  += pm[(size_t)(g * 32 + k) * 1024 + c];
        sp += pp[(size_t)(g * 32 + k) * 1024 + c];
    }
    int cnt = lbound(batch, N, g + 1) - lbound(batch, N, g);
    if (cnt < 1) cnt = 1;
    Xbar[g * 1024 + c] = s / (float)cnt;
    xsp[g * 1024 + c] = sp;
}

// npos[g] = #nodes in g with deg>0
__global__ __launch_bounds__(256) void npos_kernel(
    const int* __restrict__ deg, const int* __restrict__ batch,
    float* __restrict__ npos, int N)
{
    __shared__ int r[256];
    int g = blockIdx.x, t = threadIdx.x;
    int glo = lbound(batch, N, g);
    int ghi = lbound(batch, N, g + 1);
    int c = 0;
    for (int i = glo + t; i < ghi; i += 256) c += (deg[i] > 0) ? 1 : 0;
    r[t] = c;
    __syncthreads();
    for (int s = 128; s > 0; s >>= 1) {
        if (t < s) r[t] += r[t + s];
        __syncthreads();
    }
    if (t == 0) npos[g] = (float)r[0];
}

// ---------------------------------------------------------------------------
// WbigT [2048][1024] bf16: V weights only (transposed, BN scale folded).
// row c in [0,1024): V1 = W1[k+1024][c]*s1[c]; [1024,2048): V2.
// ---------------------------------------------------------------------------
__global__ __launch_bounds__(256) void wbig_kernel(
    const float* __restrict__ W1, const float* __restrict__ W2,
    const float* __restrict__ g1, const float* __restrict__ g2,
    ushort* __restrict__ Wt)
{
    __shared__ float tile[32][33];
    const float SF = 1.0f / sqrtf(1.0f + 1e-5f);
    int k0 = blockIdx.x * 32, c0 = blockIdx.y * 32;
    int tx = threadIdx.x & 31, ty = threadIdx.x >> 5;
    int sec = c0 >> 10;
    int cl = (c0 & 1023) + tx;
    const float* W  = sec ? W2 : W1;
    const float* gv = sec ? g2 : g1;
    float sc = gv[cl] * SF;
    #pragma unroll
    for (int j = 0; j < 4; ++j) {
        int k = k0 + ty + j * 8;
        tile[ty + j * 8][tx] = W[(size_t)(k + 1024) * 1024 + cl] * sc;
    }
    __syncthreads();
    #pragma unroll
    for (int j = 0; j < 4; ++j) {
        int cc = ty + j * 8;
        Wt[(size_t)(c0 + cc) * 1024 + k0 + tx] = f2bf(tile[tx][cc]);
    }
}

// Wfold[k][o] = sum_c W0[k][c]*s0[c]*Wr[c][o]
__global__ __launch_bounds__(256) void wfold_kernel(
    const float* __restrict__ W0, const float* __restrict__ g0,
    const float* __restrict__ Wr, float* __restrict__ Wfold)
{
    __shared__ float r0s[256], r1s[256];
    const float SF = 1.0f / sqrtf(1.0f + 1e-5f);
    int k = blockIdx.x, t = threadIdx.x;
    float a0 = 0.f, a1 = 0.f;
    for (int c = t; c < 1024; c += 256) {
        float w = W0[(size_t)k * 1024 + c] * (g0[c] * SF);
        a0 += w * Wr[c * 2];
        a1 += w * Wr[c * 2 + 1];
    }
    r0s[t] = a0; r1s[t] = a1;
    __syncthreads();
    for (int s = 128; s > 0; s >>= 1) {
        if (t < s) { r0s[t] += r0s[t + s]; r1s[t] += r1s[t + s]; }
        __syncthreads();
    }
    if (t == 0) { Wfold[k * 2] = r0s[0]; Wfold[k * 2 + 1] = r1s[0]; }
}

// Wufold[k][o] = sum_c [(W1[k][c]-W1[k+1024][c])*s1[c]
//                     + (W2[k][c]-W2[k+1024][c])*s2[c]] * Wr[c][o]
__global__ __launch_bounds__(256) void wufold_kernel(
    const float* __restrict__ W1, const float* __restrict__ W2,
    const float* __restrict__ g1, const float* __restrict__ g2,
    const float* __restrict__ Wr, float* __restrict__ Wufold)
{
    __shared__ float r0s[256], r1s[256];
    const float SF = 1.0f / sqrtf(1.0f + 1e-5f);
    int k = blockIdx.x, t = threadIdx.x;
    float a0 = 0.f, a1 = 0.f;
    for (int c = t; c < 1024; c += 256) {
        float wu = (W1[(size_t)k * 1024 + c] - W1[(size_t)(k + 1024) * 1024 + c]) * (g1[c] * SF)
                 + (W2[(size_t)k * 1024 + c] - W2[(size_t)(k + 1024) * 1024 + c]) * (g2[c] * SF);
        a0 += wu * Wr[c * 2];
        a1 += wu * Wr[c * 2 + 1];
    }
    r0s[t] = a0; r1s[t] = a1;
    __syncthreads();
    for (int s = 128; s > 0; s >>= 1) {
        if (t < s) { r0s[t] += r0s[t + s]; r1s[t] += r1s[t + s]; }
        __syncthreads();
    }
    if (t == 0) { Wufold[k * 2] = r0s[0]; Wufold[k * 2 + 1] = r1s[0]; }
}

// bUWr[o] = sum_c [b1*s1+be1 + b2*s2+be2](c) * Wr[c][o]
__global__ __launch_bounds__(256) void bfold_kernel(
    const float* __restrict__ b1, const float* __restrict__ g1, const float* __restrict__ be1,
    const float* __restrict__ b2, const float* __restrict__ g2, const float* __restrict__ be2,
    const float* __restrict__ Wr, float* __restrict__ bUWr)
{
    __shared__ float r0s[256], r1s[256];
    const float SF = 1.0f / sqrtf(1.0f + 1e-5f);
    int t = threadIdx.x;
    float a0 = 0.f, a1 = 0.f;
    for (int c = t; c < 1024; c += 256) {
        float bu = b1[c] * (g1[c] * SF) + be1[c] + b2[c] * (g2[c] * SF) + be2[c];
        a0 += bu * Wr[c * 2];
        a1 += bu * Wr[c * 2 + 1];
    }
    r0s[t] = a0; r1s[t] = a1;
    __syncthreads();
    for (int s = 128; s > 0; s >>= 1) {
        if (t < s) { r0s[t] += r0s[t + s]; r1s[t] += r1s[t + s]; }
        __syncthreads();
    }
    if (t == 0) { bUWr[0] = r0s[0]; bUWr[1] = r1s[0]; }
}

// ---------------------------------------------------------------------------
// 256x256-tile 8-phase bf16 GEMM. C[65536][2048] = A @ Wt^T (V1|V2, no bias).
// Epilogue: LDS restage (XOR ((ml&7)<<3), <=2-way banks) + dwordx4 stores.
// ---------------------------------------------------------------------------
__global__ __launch_bounds__(512, 2) void gemm8_kernel(
    const ushort* __restrict__ A, const ushort* __restrict__ Bt,
    ushort* __restrict__ C)
{
    __shared__ __align__(16) ushort SM[65536];   // 128 KiB
    const int tid  = threadIdx.x;
    const int w    = tid >> 6;
    const int lane = tid & 63;
    const int wr = w >> 2;
    const int wc = w & 3;

    const int bx  = blockIdx.x;
    const int swz = (bx & 7) * 256 + (bx >> 3);
    const int m0 = (swz >> 3) * 256;
    const int n0 = (swz & 7) * 256;

    const int srow = lane >> 3;
    const int csw  = ((lane & 7) ^ srow) << 3;

    auto stA = [&](int t, int h) {
        if (t >= 16) return;
        const int c = t & 1;
        const ushort* s = A + (size_t)(m0 + h * 128 + w * 8 + srow) * 1024 + t * 64 + csw;
        ushort* d = SM + c * 16384 + h * 8192 + w * 512;
        load_lds16(s, d);
        load_lds16(s + (size_t)64 * 1024, d + 4096);
    };
    auto stB = [&](int t, int h) {
        if (t >= 16) return;
        const int c = t & 1;
        const ushort* s = Bt + (size_t)(n0 + h * 128 + w * 8 + srow) * 1024 + t * 64 + csw;
        ushort* d = SM + 32768 + c * 16384 + h * 8192 + w * 512;
        load_lds16(s, d);
        load_lds16(s + (size_t)64 * 1024, d + 4096);
    };

    const int cbk0 = ((lane >> 4) << 4);
    const int cbx  = (lane & 7) << 4;
    auto rdA = [&](int c, int i, int kk) -> short8 {
        int row = i * 16 + (lane & 15);
        int cb  = (kk * 64 + cbk0) ^ cbx;
        return *(const short8*)((const char*)SM + (c * 16384 + wr * 8192) * 2 + row * 128 + cb);
    };
    auto rdB = [&](int c, int j, int kk) -> short8 {
        int row = (wc & 1) * 64 + j * 16 + (lane & 15);
        int cb  = (kk * 64 + cbk0) ^ cbx;
        return *(const short8*)((const char*)SM + 65536 + (c * 16384 + (wc >> 1) * 8192) * 2 + row * 128 + cb);
    };

    f32x4 acc[8][4];
    #pragma unroll
    for (int i = 0; i < 8; ++i)
        #pragma unroll
        for (int j = 0; j < 4; ++j)
            acc[i][j] = (f32x4){0.f, 0.f, 0.f, 0.f};

    short8 afr[4][2], bfr[4][2];

    stA(0, 0); stA(0, 1); stB(0, 0); stB(0, 1); stB(1, 0); stB(1, 1);
    asm volatile("s_waitcnt vmcnt(4)" ::: "memory");
    __builtin_amdgcn_s_barrier();

    for (int t = 0; t < 16; ++t) {
        const int c = t & 1;
        // P1
        #pragma unroll
        for (int i = 0; i < 4; ++i) { afr[i][0] = rdA(c, i, 0); afr[i][1] = rdA(c, i, 1); }
        #pragma unroll
        for (int j = 0; j < 2; ++j) { bfr[j][0] = rdB(c, j, 0); bfr[j][1] = rdB(c, j, 1); }
        stA(t + 1, 0);
        __builtin_amdgcn_s_barrier();
        __builtin_amdgcn_s_setprio(1);
        #pragma unroll
        for (int i = 0; i < 4; ++i)
            #pragma unroll
            for (int j = 0; j < 2; ++j) {
                acc[i][j] = __builtin_amdgcn_mfma_f32_16x16x32_bf16(bfr[j][0], afr[i][0], acc[i][j], 0, 0, 0);
                acc[i][j] = __builtin_amdgcn_mfma_f32_16x16x32_bf16(bfr[j][1], afr[i][1], acc[i][j], 0, 0, 0);
            }
        __builtin_amdgcn_s_setprio(0);
        __builtin_amdgcn_s_barrier();

        // P2
        #pragma unroll
        for (int j = 2; j < 4; ++j) { bfr[j][0] = rdB(c, j, 0); bfr[j][1] = rdB(c, j, 1); }
        stA(t + 1, 1);
        __builtin_amdgcn_s_barrier();
        __builtin_amdgcn_s_setprio(1);
        #pragma unroll
        for (int i = 0; i < 4; ++i)
            #pragma unroll
            for (int j = 2; j < 4; ++j) {
                acc[i][j] = __builtin_amdgcn_mfma_f32_16x16x32_bf16(bfr[j][0], afr[i][0], acc[i][j], 0, 0, 0);
                acc[i][j] = __builtin_amdgcn_mfma_f32_16x16x32_bf16(bfr[j][1], afr[i][1], acc[i][j], 0, 0, 0);
            }
        __builtin_amdgcn_s_setprio(0);
        __builtin_amdgcn_s_barrier();

        // P3
        #pragma unroll
        for (int i = 0; i < 4; ++i) { afr[i][0] = rdA(c, i + 4, 0); afr[i][1] = rdA(c, i + 4, 1); }
        stB(t + 2, 0);
        __builtin_amdgcn_s_barrier();
        __builtin_amdgcn_s_setprio(1);
        #pragma unroll
        for (int i = 0; i < 4; ++i)
            #pragma unroll
            for (int j = 2; j < 4; ++j) {
                acc[i + 4][j] = __builtin_amdgcn_mfma_f32_16x16x32_bf16(bfr[j][0], afr[i][0], acc[i + 4][j], 0, 0, 0);
                acc[i + 4][j] = __builtin_amdgcn_mfma_f32_16x16x32_bf16(bfr[j][1], afr[i][1], acc[i + 4][j], 0, 0, 0);
            }
        __builtin_amdgcn_s_setprio(0);
        __builtin_amdgcn_s_barrier();

        // P4
        stB(t + 2, 1);
        __builtin_amdgcn_s_barrier();
        __builtin_amdgcn_s_setprio(1);
        #pragma unroll
        for (int i = 0; i < 4; ++i)
            #pragma unroll
            for (int j = 0; j < 2; ++j) {
                acc[i + 4][j] = __builtin_amdgcn_mfma_f32_16x16x32_bf16(bfr[j][0], afr[i][0], acc[i + 4][j], 0, 0, 0);
                acc[i + 4][j] = __builtin_amdgcn_mfma_f32_16x16x32_bf16(bfr[j][1], afr[i][1], acc[i + 4][j], 0, 0, 0);
            }
        __builtin_amdgcn_s_setprio(0);
        if (t < 15) {
            if (t < 14) asm volatile("s_waitcnt vmcnt(4)" ::: "memory");
            else        asm volatile("s_waitcnt vmcnt(0)" ::: "memory");
            __builtin_amdgcn_s_barrier();
        }
    }

    // epilogue (swapped D): lane = row (wr*128+i*16+(lane&15)) x 4 consecutive
    // cols (wc*64 + j*16 + (lane>>4)*4). XOR ((ml&7)<<3) ushorts: <=2-way banks.
    __syncthreads();
    {
        const int mls = wr * 128 + (lane & 15);
        const int nls = wc * 64 + ((lane >> 4) << 2);
        #pragma unroll
        for (int j = 0; j < 4; ++j) {
            const int nl = nls + j * 16;
            #pragma unroll
            for (int i = 0; i < 8; ++i) {
                const int ml = mls + i * 16;
                unsigned lo = (unsigned)f2bf(acc[i][j][0]) |
                              ((unsigned)f2bf(acc[i][j][1]) << 16);
                unsigned hi = (unsigned)f2bf(acc[i][j][2]) |
                              ((unsigned)f2bf(acc[i][j][3]) << 16);
                int u = (ml * 256 + nl) ^ ((ml & 7) << 3);
                *(uint2*)(SM + u) = make_uint2(lo, hi);
            }
        }
    }
    __syncthreads();
    #pragma unroll
    for (int p = 0; p < 16; ++p) {
        const int row = p * 16 + (tid >> 5);
        const int cu  = (tid & 31) * 8;
        int u = (row * 256 + cu) ^ ((row & 7) << 3);
        short8 v = *(const short8*)(SM + u);
        *(short8*)(&C[(size_t)(m0 + row) * 2048 + n0 + cu]) = v;
    }
}

// ---------------------------------------------------------------------------
// Fused gather-max + pool partials over BOTH blocks' V (2048 cols).
// Block = (g, sub) of 64x16; thread owns 8 cols (short8 loads, 8 fmax chains).
// partial[g*16+sub][d] = sum over deg>0 nodes of max_src V[src][d]
// ---------------------------------------------------------------------------
__global__ __launch_bounds__(256) void edgepool_kernel(
    const ushort* __restrict__ C, const int* __restrict__ rowptr,
    const int* __restrict__ colb, const int* __restrict__ batch,
    float* __restrict__ partial, int N)
{
    const int b = blockIdx.x;          // 64*16
    const int g = b >> 4, sub = b & 15;
    const int d8 = threadIdx.x * 8;

    const int glo = lbound(batch, N, g);
    const int ghi = lbound(batch, N, g + 1);
    const int len = ghi - glo;
    const int s0 = glo + (len * sub) / 16;
    const int s1 = glo + (len * (sub + 1)) / 16;

    float vsum[8];
    #pragma unroll
    for (int q = 0; q < 8; ++q) vsum[q] = 0.f;

    int lo = (s0 < s1) ? rowptr[s0] : 0;
    for (int node = s0; node < s1; ++node) {
        int hi = rowptr[node + 1];
        if (hi > lo) {
            float vmax[8];
            #pragma unroll
            for (int q = 0; q < 8; ++q) vmax[q] = -3.4e38f;
            for (int j = lo; j < hi; ++j) {
                int src = colb[j];
                short8 v = *(const short8*)(C + (size_t)src * 2048 + d8);
                #pragma unroll
                for (int q = 0; q < 8; ++q)
                    vmax[q] = fmaxf(vmax[q], bf2f((ushort)v[q]));
            }
            #pragma unroll
            for (int q = 0; q < 8; ++q) vsum[q] += vmax[q];
        }
        lo = hi;
    }
    float* p = partial + (size_t)(g * 16 + sub) * 2048 + d8;
    *(float4*)(p)     = make_float4(vsum[0], vsum[1], vsum[2], vsum[3]);
    *(float4*)(p + 4) = make_float4(vsum[4], vsum[5], vsum[6], vsum[7]);
}

// accb[g][c] = sum_sub (partial[c] + partial[c+1024]) / cnt   (V1+V2 merged)
__global__ __launch_bounds__(256) void poolreduce_kernel(
    const float* __restrict__ partial, const int* __restrict__ batch,
    float* __restrict__ acc, int N)
{
    int g = blockIdx.x >> 2;
    int c = ((blockIdx.x & 3) << 8) + threadIdx.x;
    float s = 0.f;
    #pragma unroll
    for (int k = 0; k < 16; ++k) {
        const float* p = partial + (size_t)(g * 16 + k) * 2048;
        s += p[c] + p[c + 1024];
    }
    int cnt = lbound(batch, N, g + 1) - lbound(batch, N, g);
    if (cnt < 1) cnt = 1;
    acc[g * 1024 + c] = s / (float)cnt;
}

// out[g][o] = br[o] + sum_c (accb + b0*s0+be0)*Wr + Xbar*Wfold
//           + (sum_k xsum_pos*Wufold + npos*bUWr)/cnt
__global__ __launch_bounds__(256) void final_kernel(
    const float* __restrict__ acc, const float* __restrict__ Xbar,
    const float* __restrict__ xsp, const float* __restrict__ npos,
    const float* __restrict__ Wfold, const float* __restrict__ Wufold,
    const float* __restrict__ bUWr, const float* __restrict__ Wr,
    const float* __restrict__ b0, const float* __restrict__ g0,
    const float* __restrict__ be0, const float* __restrict__ br,
    const int* __restrict__ batch, float* __restrict__ out, int N)
{
    __shared__ float r0[256], r1[256], r2[256], r3[256];
    const float SF = 1.0f / sqrtf(1.0f + 1e-5f);
    int g = blockIdx.x, t = threadIdx.x;
    float p0 = 0.f, p1 = 0.f, q0 = 0.f, q1 = 0.f;
    for (int c = t; c < 1024; c += 256) {
        float a = acc[g * 1024 + c] + b0[c] * (g0[c] * SF) + be0[c];
        p0 += a * Wr[c * 2];
        p1 += a * Wr[c * 2 + 1];
        float xb = Xbar[g * 1024 + c];
        p0 += xb * Wfold[c * 2];
        p1 += xb * Wfold[c * 2 + 1];
        float xs = xsp[g * 1024 + c];
        q0 += xs * Wufold[c * 2];
        q1 += xs * Wufold[c * 2 + 1];
    }
    r0[t] = p0; r1[t] = p1; r2[t] = q0; r3[t] = q1;
    __syncthreads();
    for (int s = 128; s > 0; s >>= 1) {
        if (t < s) {
            r0[t] += r0[t + s]; r1[t] += r1[t + s];
            r2[t] += r2[t + s]; r3[t] += r3[t + s];
        }
        __syncthreads();
    }
    if (t == 0) {
        int cnt = lbound(batch, N, g + 1) - lbound(batch, N, g);
        if (cnt < 1) cnt = 1;
        float ic = 1.0f / (float)cnt;
        out[g * 2 + 0] = r0[0] + (r2[0] + npos[g] * bUWr[0]) * ic + br[0];
        out[g * 2 + 1] = r1[0] + (r3[0] + npos[g] * bUWr[1]) * ic + br[1];
    }
}

extern "C" void kernel_launch(void* const* d_in, const int* in_sizes, int n_in,
                              void* d_out, int out_size, void* d_ws, size_t ws_size,
                              hipStream_t stream)
{
    const float* x   = (const float*)d_in[0];
    const int*   ei  = (const int*)d_in[1];
    const int* batch = (const int*)d_in[2];
    const float* W0  = (const float*)d_in[3];
    const float* b0  = (const float*)d_in[4];
    const float* g0  = (const float*)d_in[5];
    const float* be0 = (const float*)d_in[6];
    const float* W1  = (const float*)d_in[7];
    const float* b1  = (const float*)d_in[8];
    const float* g1  = (const float*)d_in[9];
    const float* be1 = (const float*)d_in[10];
    const float* W2  = (const float*)d_in[11];
    const float* b2  = (const float*)d_in[12];
    const float* g2  = (const float*)d_in[13];
    const float* be2 = (const float*)d_in[14];
    const float* Wr  = (const float*)d_in[15];
    const float* br  = (const float*)d_in[16];
    float* out = (float*)d_out;

    const int N = in_sizes[2];       // 65536
    const int E = in_sizes[1] / 2;   // 131072

    char* ws = (char*)d_ws;
    size_t off = 0;
    auto alloc = [&](size_t bytes) -> void* {
        off = (off + 255) & ~(size_t)255;
        void* p = ws + off;
        off += bytes;
        return p;
    };
    ushort*   xh      = (ushort*)alloc((size_t)N * 1024 * 2);
    ushort*   Wt      = (ushort*)alloc((size_t)2048 * 1024 * 2);
    float*    Xbar    = (float*)alloc(64 * 1024 * 4);
    float*    xsp     = (float*)alloc(64 * 1024 * 4);
    float*    accb    = (float*)alloc(64 * 1024 * 4);
    float*    Wfold   = (float*)alloc(1024 * 2 * 4);
    float*    Wufold  = (float*)alloc(1024 * 2 * 4);
    float*    bUWr    = (float*)alloc(256);
    float*    nposb   = (float*)alloc(64 * 4);
    ushort*   Cbuf    = (ushort*)alloc((size_t)N * 2048 * 2);
    float*    partial = (float*)alloc((size_t)1024 * 2048 * 4);
    float*    pm      = (float*)alloc((size_t)2048 * 1024 * 4);
    float*    pp      = (float*)alloc((size_t)2048 * 1024 * 4);
    int*      deg     = (int*)alloc((size_t)N * 4);
    int*      rowptr  = (int*)alloc(((size_t)N + 1) * 4);
    int*      cursor  = (int*)alloc((size_t)N * 4);
    int*      colb    = (int*)alloc((size_t)E * 4);
    (void)ws_size; (void)n_in; (void)out_size;

    // CSR first (cvtmean needs deg)
    zero_kernel<<<(N + 255) / 256, 256, 0, stream>>>(deg, N);
    degcount_kernel<<<(E + 255) / 256, 256, 0, stream>>>(ei, deg, E);
    scan_kernel<<<1, 1024, 0, stream>>>(deg, rowptr, cursor, N, E);
    scatter_kernel<<<(E + 255) / 256, 256, 0, stream>>>(ei, cursor, colb, E);

    // x conversion + pooled sums; weight prep; folds
    cvtmean_kernel<<<2048, 256, 0, stream>>>(x, batch, deg, xh, pm, pp, N);
    xbar2_kernel<<<256, 256, 0, stream>>>(pm, pp, batch, Xbar, xsp, N);
    npos_kernel<<<64, 256, 0, stream>>>(deg, batch, nposb, N);
    wbig_kernel<<<dim3(32, 64), 256, 0, stream>>>(W1, W2, g1, g2, Wt);
    wfold_kernel<<<1024, 256, 0, stream>>>(W0, g0, Wr, Wfold);
    wufold_kernel<<<1024, 256, 0, stream>>>(W1, W2, g1, g2, Wr, Wufold);
    bfold_kernel<<<1, 256, 0, stream>>>(b1, g1, be1, b2, g2, be2, Wr, bUWr);

    // single V-GEMM for both blocks, then fused gather-max+pool
    gemm8_kernel<<<2048, 512, 0, stream>>>(xh, Wt, Cbuf);
    edgepool_kernel<<<1024, 256, 0, stream>>>(Cbuf, rowptr, colb, batch, partial, N);
    poolreduce_kernel<<<256, 256, 0, stream>>>(partial, batch, accb, N);

    final_kernel<<<64, 256, 0, stream>>>(accb, Xbar, xsp, nposb, Wfold, Wufold,
                                         bUWr, Wr, b0, g0, be0, br, batch, out, N);
}